// Round 1
// 550.865 us; speedup vs baseline: 1.0224x; 1.0224x over previous
//
#include <hip/hip_runtime.h>
#include <stdint.h>
#include <stddef.h>

#define AS1 __attribute__((address_space(1)))
#define AS3 __attribute__((address_space(3)))

typedef short short8 __attribute__((ext_vector_type(8)));   // 8 bf16 (4 VGPRs)
typedef float v4f    __attribute__((ext_vector_type(4)));   // MFMA C/D frag
typedef unsigned short us4 __attribute__((ext_vector_type(4)));

constexpr int S_  = 2048;
constexpr int D_  = 4096;
constexpr int H_  = 32;
constexpr int KV_ = 8;
constexpr int HD_ = 128;
constexpr int NQKV_ = H_*HD_ + 2*KV_*HD_;   // 6144
constexpr float SCALE_L2E = 0.12751744154070513f;  // (1/sqrt(128)) * log2(e)
constexpr float NLOG2T_64 = -0.24390063241307518f; // -log2(50000)/64

// 256x256 8-phase GEMM geometry (both GEMMs have K = 4096)
constexpr int GK  = 4096;
constexpr int NKT = GK / 64;   // 64 K-tiles of 64
constexpr int NIT = NKT / 2;   // 32 iterations (2 K-tiles / iter)

__device__ __forceinline__ unsigned short f2bf(float f){
  union { float f; unsigned u; } v; v.f = f;
  unsigned r = v.u + 0x7FFFu + ((v.u >> 16) & 1u);     // RNE
  return (unsigned short)(r >> 16);
}
__device__ __forceinline__ float bf2f(unsigned short h){
  union { unsigned u; float f; } v; v.u = ((unsigned)h) << 16; return v.f;
}

// async global->LDS, 16B per lane; LDS dst = wave-uniform base + lane*16
__device__ __forceinline__ void gl_lds16(const unsigned short* g, unsigned short* l){
  __builtin_amdgcn_global_load_lds((AS1 unsigned int*)(uintptr_t)g,
                                   (AS3 unsigned int*)l, 16, 0, 0);
}

// ---------------- RMSNorm: hidden fp32 [S][D] -> h bf16 [S][D] ----------------
__global__ __launch_bounds__(256) void rmsnorm_k(const float* __restrict__ hidden,
                                                 const float* __restrict__ w,
                                                 unsigned short* __restrict__ out){
  const int s = blockIdx.x, tid = threadIdx.x;
  const float4* row = (const float4*)(hidden + (size_t)s * D_);
  float4 v[4];
  float ss = 0.f;
  #pragma unroll
  for (int i = 0; i < 4; i++){
    float4 t = row[tid + 256*i]; v[i] = t;
    ss += t.x*t.x + t.y*t.y + t.z*t.z + t.w*t.w;
  }
  #pragma unroll
  for (int off = 32; off >= 1; off >>= 1) ss += __shfl_xor(ss, off, 64);
  __shared__ float wsum[4];
  if ((tid & 63) == 0) wsum[tid >> 6] = ss;
  __syncthreads();
  const float total = wsum[0] + wsum[1] + wsum[2] + wsum[3];
  const float r = rsqrtf(total * (1.0f / D_) + 1e-6f);
  const float4* w4 = (const float4*)w;
  us4* o = (us4*)(out + (size_t)s * D_);
  #pragma unroll
  for (int i = 0; i < 4; i++){
    float4 t = v[i], ww = w4[tid + 256*i];
    us4 p;
    p[0] = f2bf(t.x * r * ww.x); p[1] = f2bf(t.y * r * ww.y);
    p[2] = f2bf(t.z * r * ww.z); p[3] = f2bf(t.w * r * ww.w);
    o[tid + 256*i] = p;
  }
}

// ---------------- fp32 -> bf16 cast ----------------
__global__ __launch_bounds__(256) void cast_k(const float* __restrict__ src,
                                              unsigned short* __restrict__ dst, int n4){
  const int i = blockIdx.x * 256 + threadIdx.x;
  if (i >= n4) return;
  float4 t = ((const float4*)src)[i];
  us4 p;
  p[0] = f2bf(t.x); p[1] = f2bf(t.y); p[2] = f2bf(t.z); p[3] = f2bf(t.w);
  ((us4*)dst)[i] = p;
}

// ---------------- 256x256 8-phase bt-GEMM: C[M,N] = A[M,K]*B[N,K]^T ------------
// 512 threads = 8 waves (2M x 4N). BK=64, 2 K-tiles per iteration, 8 phases.
// LDS 128 KiB: A,B each 2 x [256][64] bf16. XOR-swizzled (T2): within a tile
// buffer, byte col ^= (row&7)<<4, realized with linear global_load_lds dst +
// pre-swizzled per-lane GLOBAL source; ds_reads apply the same XOR.
// Counted vmcnt(4) at phases 4 and 8 only (T3+T4); setprio around MFMA (T5).
#define BARRIER() do { __builtin_amdgcn_sched_barrier(0);                    \
                       __builtin_amdgcn_s_barrier();                         \
                       asm volatile("" ::: "memory"); } while(0)

#define STG_A(db, half, j, kt)                                               \
  gl_lds16(gAw + (size_t)((half)*128 + (j)*64) * GK + (size_t)(kt)*64,       \
           sA + (db)*16384 + (half)*8192 + (j)*4096 + wave*512)

#define STG_B(db, half, j, kt)                                               \
  gl_lds16(gBw + (size_t)((half)*128 + (j)*64) * GK + (size_t)(kt)*64,       \
           sB + (db)*16384 + (half)*8192 + (j)*4096 + wave*512)

#define LOAD_A(db, mh)                                                       \
  _Pragma("unroll") for (int ks = 0; ks < 2; ++ks)                           \
    _Pragma("unroll") for (int mf = 0; mf < 4; ++mf)                         \
      af[ks][mf] = *(const short8*)(sA + (db)*16384 + aRowU + ((mh)*4+mf)*1024 + cswzU[ks]);

#define LOAD_B2(db, nh)                                                      \
  _Pragma("unroll") for (int ks = 0; ks < 2; ++ks)                           \
    _Pragma("unroll") for (int nf = 0; nf < 2; ++nf)                         \
      bf[ks][(nh)*2+nf] = *(const short8*)(sB + (db)*16384 + bRowU + ((nh)*2+nf)*1024 + cswzU[ks]);

#define MFMA_Q(mh, nh) do {                                                  \
  __builtin_amdgcn_s_setprio(1);                                             \
  _Pragma("unroll") for (int mf = 0; mf < 4; ++mf)                           \
    _Pragma("unroll") for (int nf = 0; nf < 2; ++nf) {                       \
      v4f t = acc[(mh)*4+mf][(nh)*2+nf];                                     \
      t = __builtin_amdgcn_mfma_f32_16x16x32_bf16(af[0][mf], bf[0][(nh)*2+nf], t, 0, 0, 0); \
      t = __builtin_amdgcn_mfma_f32_16x16x32_bf16(af[1][mf], bf[1][(nh)*2+nf], t, 0, 0, 0); \
      acc[(mh)*4+mf][(nh)*2+nf] = t;                                         \
    }                                                                        \
  __builtin_amdgcn_s_setprio(0);                                             \
} while (0)

__global__ __launch_bounds__(512, 2) void gemm256(const unsigned short* __restrict__ A,
                                                  const unsigned short* __restrict__ B,
                                                  void* __restrict__ Cp,
                                                  int ldc, int f32out){
  __shared__ __align__(16) unsigned short sA[2*16384];   // 64 KiB: [2][256][64]
  __shared__ __align__(16) unsigned short sB[2*16384];   // 64 KiB

  const int tid = threadIdx.x;
  const int wave = tid >> 6, lane = tid & 63;
  const int l15 = lane & 15, quad = lane >> 4;
  const int wm = wave >> 2, wn = wave & 3;
  const int m0 = blockIdx.y * 256, n0 = blockIdx.x * 256;

  // staging: per-lane pre-swizzled global source (LDS dst stays linear)
  const int lrow  = lane >> 3;                        // 8 rows per wave-KB
  const int lslot = (lane & 7) ^ lrow;                // swizzled 16B slot
  const size_t laneOff = (size_t)lrow * GK + (size_t)lslot * 8;
  const unsigned short* gAw = A + (size_t)(m0 + wave*8) * GK + laneOff;
  const unsigned short* gBw = B + (size_t)(n0 + wave*8) * GK + laneOff;

  // ds_read addressing (ushort units), swizzle col ^= (l15&7)<<4 bytes
  const int aRowU = (wm*128 + l15) * 64;
  const int bRowU = (wn*64  + l15) * 64;
  int cswzU[2];
  cswzU[0] = (( 0 + quad*16) ^ ((l15 & 7) << 4)) >> 1;
  cswzU[1] = ((64 + quad*16) ^ ((l15 & 7) << 4)) >> 1;

  v4f acc[8][4];
  #pragma unroll
  for (int i = 0; i < 8; i++)
    #pragma unroll
    for (int j = 0; j < 4; j++) acc[i][j] = (v4f){0.f,0.f,0.f,0.f};

  short8 af[2][4];   // A frags: [ksub][mf-of-current-half]
  short8 bf[2][4];   // B frags: [ksub][nf 0..3]

  // prologue: B(0), A(0), B(1)  (12 loads/wave); A(1) is staged in P1/P2 of i=0
  STG_B(0,0,0,0); STG_B(0,0,1,0); STG_B(0,1,0,0); STG_B(0,1,1,0);
  STG_A(0,0,0,0); STG_A(0,0,1,0); STG_A(0,1,0,0); STG_A(0,1,1,0);
  STG_B(1,0,0,1); STG_B(1,0,1,1); STG_B(1,1,0,1); STG_B(1,1,1,1);
  asm volatile("s_waitcnt vmcnt(4)" ::: "memory");    // B(0),A(0) landed
  BARRIER();

  #pragma unroll 1
  for (int i = 0; i < NIT; ++i){
    const int t1 = 2*i + 1, t2 = 2*i + 2, t3 = 2*i + 3;
    const bool s2 = (t2 < NKT), s3 = (t3 < NKT);

    // ---- P1: tile 2i (buf0): Mf0-3 x Nf0-1; stage A(t1) h0 -> buf1 ----
    LOAD_A(0, 0); LOAD_B2(0, 0);
    STG_A(1, 0, 0, t1); STG_A(1, 0, 1, t1);
    BARRIER();
    MFMA_Q(0, 0);
    BARRIER();
    // ---- P2: Mf0-3 x Nf2-3 (A regs reused); stage A(t1) h1 ----
    LOAD_B2(0, 1);
    STG_A(1, 1, 0, t1); STG_A(1, 1, 1, t1);
    BARRIER();
    MFMA_Q(0, 1);
    BARRIER();
    // ---- P3: Mf4-7 x Nf0-1 (B regs reused); stage B(t2) h0 -> buf0 ----
    LOAD_A(0, 1);
    if (s2) { STG_B(0, 0, 0, t2); STG_B(0, 0, 1, t2); }
    BARRIER();
    MFMA_Q(1, 0);
    BARRIER();
    // ---- P4: Mf4-7 x Nf2-3 (all regs); stage B(t2) h1; counted wait ----
    if (s2) { STG_B(0, 1, 0, t2); STG_B(0, 1, 1, t2); }
    BARRIER();
    MFMA_Q(1, 1);
    if (i + 1 < NIT) asm volatile("s_waitcnt vmcnt(4)" ::: "memory"); // A(t1),B(t1) landed
    else             asm volatile("s_waitcnt vmcnt(0)" ::: "memory"); // final drain
    BARRIER();

    // ---- P5: tile 2i+1 (buf1): Mf0-3 x Nf0-1; stage A(t2) h0 -> buf0 ----
    LOAD_A(1, 0); LOAD_B2(1, 0);
    if (s2) { STG_A(0, 0, 0, t2); STG_A(0, 0, 1, t2); }
    BARRIER();
    MFMA_Q(0, 0);
    BARRIER();
    // ---- P6: Mf0-3 x Nf2-3; stage A(t2) h1 ----
    LOAD_B2(1, 1);
    if (s2) { STG_A(0, 1, 0, t2); STG_A(0, 1, 1, t2); }
    BARRIER();
    MFMA_Q(0, 1);
    BARRIER();
    // ---- P7: Mf4-7 x Nf0-1; stage B(t3) h0 -> buf1 ----
    LOAD_A(1, 1);
    if (s3) { STG_B(1, 0, 0, t3); STG_B(1, 0, 1, t3); }
    BARRIER();
    MFMA_Q(1, 0);
    BARRIER();
    // ---- P8: Mf4-7 x Nf2-3; stage B(t3) h1; counted wait ----
    if (s3) { STG_B(1, 1, 0, t3); STG_B(1, 1, 1, t3); }
    BARRIER();
    MFMA_Q(1, 1);
    asm volatile("s_waitcnt vmcnt(4)" ::: "memory");   // A(t2),B(t2) landed
    BARRIER();
  }

  // ---- epilogue ----
  if (f32out){
    float* Cf = (float*)Cp;
    #pragma unroll
    for (int mf = 0; mf < 8; ++mf)
      #pragma unroll
      for (int r = 0; r < 4; ++r){
        const size_t row = (size_t)(m0 + wm*128 + mf*16 + quad*4 + r);
        float* crow = Cf + row * ldc + n0 + wn*64 + l15;
        #pragma unroll
        for (int nf = 0; nf < 4; ++nf) crow[nf*16] = acc[mf][nf][r];
      }
  } else {
    unsigned short* Cb = (unsigned short*)Cp;
    #pragma unroll
    for (int mf = 0; mf < 8; ++mf)
      #pragma unroll
      for (int r = 0; r < 4; ++r){
        const size_t row = (size_t)(m0 + wm*128 + mf*16 + quad*4 + r);
        unsigned short* crow = Cb + row * ldc + n0 + wn*64 + l15;
        #pragma unroll
        for (int nf = 0; nf < 4; ++nf) crow[nf*16] = f2bf(acc[mf][nf][r]);
      }
  }
}

// ---- RoPE on Q (PRE-SCALED by 1/sqrt(HD)*log2e): qkv -> qa[h][s][128] ----
__global__ __launch_bounds__(256) void rope_q_k(const unsigned short* __restrict__ qkv,
                                                unsigned short* __restrict__ qa){
  const int idx = blockIdx.x * 256 + threadIdx.x;
  const int j = idx & 63, h = (idx >> 6) & (H_-1), s = idx >> 11;
  const unsigned pair = *(const unsigned*)(qkv + (size_t)s*NQKV_ + h*HD_ + 2*j);
  const float x0 = bf2f((unsigned short)(pair & 0xffffu));
  const float x1 = bf2f((unsigned short)(pair >> 16));
  const float ang = (float)s * exp2f((float)j * NLOG2T_64);
  const float c = __cosf(ang), sn = __sinf(ang);
  const unsigned o = (unsigned)f2bf((x0*c - x1*sn) * SCALE_L2E)
                   | ((unsigned)f2bf((x0*sn + x1*c) * SCALE_L2E) << 16);
  *(unsigned*)(qa + ((size_t)h*S_ + s)*HD_ + 2*j) = o;
}

// ---------------- RoPE on K: qkv[s][4096+kv*128+..] -> ka[kv][s][128] ------------
__global__ __launch_bounds__(256) void rope_kk(const unsigned short* __restrict__ qkv,
                                               unsigned short* __restrict__ ka){
  const int idx = blockIdx.x * 256 + threadIdx.x;
  const int j = idx & 63, kv = (idx >> 6) & (KV_-1), s = idx >> 9;
  const unsigned pair = *(const unsigned*)(qkv + (size_t)s*NQKV_ + H_*HD_ + kv*HD_ + 2*j);
  const float x0 = bf2f((unsigned short)(pair & 0xffffu));
  const float x1 = bf2f((unsigned short)(pair >> 16));
  const float ang = (float)s * exp2f((float)j * NLOG2T_64);
  const float c = __cosf(ang), sn = __sinf(ang);
  const unsigned o = (unsigned)f2bf(x0*c - x1*sn) | ((unsigned)f2bf(x0*sn + x1*c) << 16);
  *(unsigned*)(ka + ((size_t)kv*S_ + s)*HD_ + 2*j) = o;
}

// ---------------- V transpose: qkv[s][5120+kv*128+d] -> vt[kv][d][s] -------------
__global__ __launch_bounds__(256) void vtrans_k(const unsigned short* __restrict__ qkv,
                                                unsigned short* __restrict__ vt){
  const int idx = blockIdx.x * 256 + threadIdx.x;
  const int s = idx & (S_-1), d = (idx >> 11) & (HD_-1), kv = idx >> 18;
  vt[idx] = qkv[(size_t)s*NQKV_ + (H_+KV_)*HD_ + kv*HD_ + d];
}

// ---------------- flash attention (causal, GQA), paired q-tiles ----------------
__device__ __forceinline__ void stage_kv(const unsigned short* __restrict__ ka,
                                         const unsigned short* __restrict__ vt,
                                         unsigned short* sKbuf, unsigned short* sVbuf,
                                         int hk, int t0, int wave, int lane){
  const int l15 = lane & 15, quad = lane >> 4;
  #pragma unroll
  for (int j = 0; j < 4; j++){
    const int c = wave*4 + j;                 // (kt,kk) = (c>>2, c&3)
    const int kt = c >> 2, kk = c & 3;
    gl_lds16(ka + (size_t)(hk*S_ + t0 + kt*16 + l15)*HD_ + kk*32 + quad*8,
             sKbuf + c*512);
  }
  #pragma unroll
  for (int j = 0; j < 4; j++){
    const int c = wave*4 + j;                 // (nt,kk2) = (c>>1, c&1)
    const int nt = c >> 1, kk2 = c & 1;
    gl_lds16(vt + (size_t)(hk*HD_ + nt*16 + l15)*S_ + t0 + kk2*32 + quad*8,
             sVbuf + c*512);
  }
}

__global__ __launch_bounds__(256, 2) void attn_k(const unsigned short* __restrict__ qa,
                                                 const unsigned short* __restrict__ ka,
                                                 const unsigned short* __restrict__ vt,
                                                 unsigned short* __restrict__ out){
  const int h = blockIdx.x, p = blockIdx.y;
  const int tid = threadIdx.x, wave = tid >> 6, lane = tid & 63;
  const int l15 = lane & 15, quad = lane >> 4;
  const int hk = h >> 2;                      // N_REP = 4
  const int nbB = 32 - p;                     // units for heavy tile (31-p)
  const int total = nbB + p + 1;              // 33 always

  __shared__ __align__(16) unsigned short sK[2][8192];   // 16KB x2
  __shared__ __align__(16) unsigned short sV[2][8192];   // 16KB x2
  __shared__ __align__(16) unsigned short sP[4][1024];   // 2KB per wave
  unsigned short* pl = &sP[wave][0];

  short8 ones;
  #pragma unroll
  for (int i = 0; i < 8; i++) ones[i] = (short)0x3F80;   // bf16 1.0

  int tile = 31 - p;
  short8 qf[4];
  {
    const unsigned short* qb = qa + (size_t)(h*S_ + tile*64 + wave*16 + l15)*HD_ + quad*8;
    #pragma unroll
    for (int kk = 0; kk < 4; kk++) qf[kk] = *(const short8*)(qb + kk*32);
  }

  v4f O[8];
  #pragma unroll
  for (int nt = 0; nt < 8; nt++) O[nt] = (v4f){0.f,0.f,0.f,0.f};
  float mrow[4], lrow[4];
  #pragma unroll
  for (int r = 0; r < 4; r++){ mrow[r] = -1e30f; lrow[r] = 0.f; }

  stage_kv(ka, vt, sK[0], sV[0], hk, 0, wave, lane);
  __syncthreads();

  for (int u = 0; u < total; ++u){
    const int cur = u & 1;
    if (u + 1 < total){
      const int b2 = (u + 1 < nbB) ? u + 1 : u + 1 - nbB;
      stage_kv(ka, vt, sK[cur^1], sV[cur^1], hk, b2*64, wave, lane);
    }

    // ---- QK^T: S[16 q-rows x 64 keys] ----
    const unsigned short* Kb = &sK[cur][0];
    v4f sc[4];
    #pragma unroll
    for (int kt = 0; kt < 4; kt++) sc[kt] = (v4f){0.f,0.f,0.f,0.f};
    #pragma unroll
    for (int kt = 0; kt < 4; kt++)
      #pragma unroll
      for (int kk = 0; kk < 4; kk++){
        const short8 kf = *(const short8*)(Kb + (kt*4 + kk)*512 + lane*8);
        sc[kt] = __builtin_amdgcn_mfma_f32_16x16x32_bf16(qf[kk], kf, sc[kt], 0, 0, 0);
      }

    // ---- online softmax (exp2 domain; Q pre-scaled) ----
    const bool diag = (u == nbB - 1) || (u == total - 1);   // wave-uniform
    float alpha[4];
    #pragma unroll
    for (int r = 0; r < 4; r++){
      float a0 = sc[0][r], a1 = sc[1][r], a2 = sc[2][r], a3 = sc[3][r];
      if (diag){
        const int rloc = wave*16 + quad*4 + r;
        if (     l15 > rloc) a0 = -1e30f;
        if (16 + l15 > rloc) a1 = -1e30f;
        if (32 + l15 > rloc) a2 = -1e30f;
        if (48 + l15 > rloc) a3 = -1e30f;
      }
      float mx = fmaxf(fmaxf(a0, a1), fmaxf(a2, a3));
      #pragma unroll
      for (int off = 1; off < 16; off <<= 1) mx = fmaxf(mx, __shfl_xor(mx, off, 16));
      const float mnew = fmaxf(mrow[r], mx);
      alpha[r] = exp2f(mrow[r] - mnew);
      mrow[r] = mnew;
      const float e0 = exp2f(a0 - mnew);
      const float e1 = exp2f(a1 - mnew);
      const float e2 = exp2f(a2 - mnew);
      const float e3 = exp2f(a3 - mnew);
      const int mr = (quad*4 + r)*8 + (l15 & 7);
      const int hi = (l15 >> 3) * 128;
      pl[      hi       + mr] = f2bf(e0);     // kt=0: kk2=0, q'=0..1
      pl[      hi + 256 + mr] = f2bf(e1);     // kt=1: kk2=0, q'=2..3
      pl[512 + hi       + mr] = f2bf(e2);     // kt=2: kk2=1, q'=0..1
      pl[512 + hi + 256 + mr] = f2bf(e3);     // kt=3: kk2=1, q'=2..3
    }
    #pragma unroll
    for (int nt = 0; nt < 8; nt++)
      #pragma unroll
      for (int r = 0; r < 4; r++) O[nt][r] *= alpha[r];

    __builtin_amdgcn_s_waitcnt(0xC07F);       // lgkmcnt(0): per-wave P region ready
    const short8 pf0 = *(const short8*)(pl + lane*8);
    const short8 pf1 = *(const short8*)(pl + 512 + lane*8);

    // ---- row-sum of P via ones-MFMA (every lane gets its row's sum) ----
    v4f rs = (v4f){0.f,0.f,0.f,0.f};
    rs = __builtin_amdgcn_mfma_f32_16x16x32_bf16(pf0, ones, rs, 0, 0, 0);
    rs = __builtin_amdgcn_mfma_f32_16x16x32_bf16(pf1, ones, rs, 0, 0, 0);

    // ---- PV: O[16 q-rows x 128 dims] ----
    const unsigned short* Vb = &sV[cur][0];
    #pragma unroll
    for (int nt = 0; nt < 8; nt++){
      const short8 vf0 = *(const short8*)(Vb + (nt*2    )*512 + lane*8);
      const short8 vf1 = *(const short8*)(Vb + (nt*2 + 1)*512 + lane*8);
      O[nt] = __builtin_amdgcn_mfma_f32_16x16x32_bf16(pf0, vf0, O[nt], 0, 0, 0);
      O[nt] = __builtin_amdgcn_mfma_f32_16x16x32_bf16(pf1, vf1, O[nt], 0, 0, 0);
    }
    #pragma unroll
    for (int r = 0; r < 4; r++) lrow[r] = lrow[r]*alpha[r] + rs[r];

    __syncthreads();   // all waves done with cur before it is overwritten

    if (u == nbB - 1){                        // finalize heavy tile, switch to light
      #pragma unroll
      for (int r = 0; r < 4; r++){
        const float inv = 1.0f / lrow[r];
        const size_t row = (size_t)(tile*64 + wave*16 + quad*4 + r);
        #pragma unroll
        for (int nt = 0; nt < 8; nt++)
          out[row*D_ + h*HD_ + nt*16 + l15] = f2bf(O[nt][r] * inv);
      }
      tile = p;
      const unsigned short* qb = qa + (size_t)(h*S_ + tile*64 + wave*16 + l15)*HD_ + quad*8;
      #pragma unroll
      for (int kk = 0; kk < 4; kk++) qf[kk] = *(const short8*)(qb + kk*32);
      #pragma unroll
      for (int nt = 0; nt < 8; nt++) O[nt] = (v4f){0.f,0.f,0.f,0.f};
      #pragma unroll
      for (int r = 0; r < 4; r++){ mrow[r] = -1e30f; lrow[r] = 0.f; }
    }
  }

  #pragma unroll
  for (int r = 0; r < 4; r++){
    const float inv = 1.0f / lrow[r];
    const size_t row = (size_t)(tile*64 + wave*16 + quad*4 + r);
    #pragma unroll
    for (int nt = 0; nt < 8; nt++)
      out[row*D_ + h*HD_ + nt*16 + l15] = f2bf(O[nt][r] * inv);
  }
}

// ---------------- launch ----------------
// Workspace map (MiB): [0,16) h_bf16 | [16,64) wqkv_bf16 (later: [16,48) wo_bf16,
// [48,64) attn_bf16) | [64,88) qkv_bf16 | [88,104) qa | [104,108) ka | [108,112) vt.
extern "C" void kernel_launch(void* const* d_in, const int* in_sizes, int n_in,
                              void* d_out, int out_size, void* d_ws, size_t ws_size,
                              hipStream_t stream){
  (void)in_sizes; (void)n_in; (void)out_size; (void)ws_size;
  const float* hidden = (const float*)d_in[0];
  const float* norm_w = (const float*)d_in[1];
  const float* wq = (const float*)d_in[2];
  const float* wk = (const float*)d_in[3];
  const float* wv = (const float*)d_in[4];
  const float* wo = (const float*)d_in[5];

  char* ws = (char*)d_ws;
  unsigned short* h_bf  = (unsigned short*)(ws);
  unsigned short* wqkv  = (unsigned short*)(ws + (size_t)(16u) * 1048576u);
  unsigned short* qkv   = (unsigned short*)(ws + (size_t)(64u) * 1048576u);
  unsigned short* qa    = (unsigned short*)(ws + (size_t)(88u) * 1048576u);
  unsigned short* ka    = (unsigned short*)(ws + (size_t)(104u) * 1048576u);
  unsigned short* vt    = (unsigned short*)(ws + (size_t)(108u) * 1048576u);
  unsigned short* wo_bf = (unsigned short*)(ws + (size_t)(16u) * 1048576u);  // reuse
  unsigned short* attnb = (unsigned short*)(ws + (size_t)(48u) * 1048576u);  // reuse

  rmsnorm_k<<<S_, 256, 0, stream>>>(hidden, norm_w, h_bf);

  cast_k<<<(D_*D_/4)/256, 256, 0, stream>>>(wq, wqkv, D_*D_/4);
  cast_k<<<(KV_*HD_*D_/4)/256, 256, 0, stream>>>(wk, wqkv + (size_t)H_*HD_*D_, KV_*HD_*D_/4);
  cast_k<<<(KV_*HD_*D_/4)/256, 256, 0, stream>>>(wv, wqkv + (size_t)(H_+KV_)*HD_*D_, KV_*HD_*D_/4);

  gemm256<<<dim3(NQKV_/256, S_/256), 512, 0, stream>>>(h_bf, wqkv, qkv, NQKV_, 0);

  rope_q_k<<<(S_*H_*64)/256, 256, 0, stream>>>(qkv, qa);
  rope_kk <<<(S_*KV_*64)/256, 256, 0, stream>>>(qkv, ka);
  vtrans_k<<<(KV_*HD_*S_)/256, 256, 0, stream>>>(qkv, vt);

  cast_k<<<(D_*D_/4)/256, 256, 0, stream>>>(wo, wo_bf, D_*D_/4);

  attn_k<<<dim3(H_, 16), 256, 0, stream>>>(qa, ka, vt, attnb);

  gemm256<<<dim3(D_/256, S_/256), 512, 0, stream>>>(attnb, wo_bf, d_out, D_, 1);
}

// Round 2
// 544.538 us; speedup vs baseline: 1.0343x; 1.0116x over previous
//
#include <hip/hip_runtime.h>
#include <stdint.h>
#include <stddef.h>

#define AS1 __attribute__((address_space(1)))
#define AS3 __attribute__((address_space(3)))

typedef short short8 __attribute__((ext_vector_type(8)));   // 8 bf16 (4 VGPRs)
typedef float v4f    __attribute__((ext_vector_type(4)));   // MFMA C/D frag
typedef unsigned short us4 __attribute__((ext_vector_type(4)));

constexpr int S_  = 2048;
constexpr int D_  = 4096;
constexpr int H_  = 32;
constexpr int KV_ = 8;
constexpr int HD_ = 128;
constexpr int NQKV_ = H_*HD_ + 2*KV_*HD_;   // 6144
constexpr float SCALE_L2E = 0.12751744154070513f;  // (1/sqrt(128)) * log2(e)
constexpr float NLOG2T_64 = -0.24390063241307518f; // -log2(50000)/64

// 256x256 8-phase GEMM geometry (both GEMMs have K = 4096)
constexpr int GK  = 4096;
constexpr int NKT = GK / 64;   // 64 K-tiles of 64
constexpr int NIT = NKT / 2;   // 32 iterations (2 K-tiles / iter)

__device__ __forceinline__ unsigned short f2bf(float f){
  union { float f; unsigned u; } v; v.f = f;
  unsigned r = v.u + 0x7FFFu + ((v.u >> 16) & 1u);     // RNE
  return (unsigned short)(r >> 16);
}
__device__ __forceinline__ float bf2f(unsigned short h){
  union { unsigned u; float f; } v; v.u = ((unsigned)h) << 16; return v.f;
}

// async global->LDS, 16B per lane; LDS dst = wave-uniform base + lane*16
__device__ __forceinline__ void gl_lds16(const unsigned short* g, unsigned short* l){
  __builtin_amdgcn_global_load_lds((AS1 unsigned int*)(uintptr_t)g,
                                   (AS3 unsigned int*)l, 16, 0, 0);
}

// ---------------- RMSNorm: hidden fp32 [S][D] -> h bf16 [S][D] ----------------
__global__ __launch_bounds__(256) void rmsnorm_k(const float* __restrict__ hidden,
                                                 const float* __restrict__ w,
                                                 unsigned short* __restrict__ out){
  const int s = blockIdx.x, tid = threadIdx.x;
  const float4* row = (const float4*)(hidden + (size_t)s * D_);
  float4 v[4];
  float ss = 0.f;
  #pragma unroll
  for (int i = 0; i < 4; i++){
    float4 t = row[tid + 256*i]; v[i] = t;
    ss += t.x*t.x + t.y*t.y + t.z*t.z + t.w*t.w;
  }
  #pragma unroll
  for (int off = 32; off >= 1; off >>= 1) ss += __shfl_xor(ss, off, 64);
  __shared__ float wsum[4];
  if ((tid & 63) == 0) wsum[tid >> 6] = ss;
  __syncthreads();
  const float total = wsum[0] + wsum[1] + wsum[2] + wsum[3];
  const float r = rsqrtf(total * (1.0f / D_) + 1e-6f);
  const float4* w4 = (const float4*)w;
  us4* o = (us4*)(out + (size_t)s * D_);
  #pragma unroll
  for (int i = 0; i < 4; i++){
    float4 t = v[i], ww = w4[tid + 256*i];
    us4 p;
    p[0] = f2bf(t.x * r * ww.x); p[1] = f2bf(t.y * r * ww.y);
    p[2] = f2bf(t.z * r * ww.z); p[3] = f2bf(t.w * r * ww.w);
    o[tid + 256*i] = p;
  }
}

// ---------------- fp32 -> bf16 cast ----------------
__global__ __launch_bounds__(256) void cast_k(const float* __restrict__ src,
                                              unsigned short* __restrict__ dst, int n4){
  const int i = blockIdx.x * 256 + threadIdx.x;
  if (i >= n4) return;
  float4 t = ((const float4*)src)[i];
  us4 p;
  p[0] = f2bf(t.x); p[1] = f2bf(t.y); p[2] = f2bf(t.z); p[3] = f2bf(t.w);
  ((us4*)dst)[i] = p;
}

// ---------------- 256x256 8-phase bt-GEMM: C[M,N] = A[M,K]*B[N,K]^T ------------
// 512 threads = 8 waves (2M x 4N). BK=64, 2 K-tiles per iteration, 8 phases,
// ONE barrier per phase. Balanced ds_reads 8/4/8/4 via early B-pair loads in
// P4/P8 (into dead bf01 regs, after the covering wait). Derived counted waits:
// vmcnt(4)@P3, vmcnt(4)@P6, vmcnt(6)@P8 (4-10 loads always in flight).
// Safety: every phase's ds_reads are consumed by that phase's MFMA (so they
// complete before the wave reaches the phase barrier); every stage targets a
// buffer whose last reader finished >=1 barrier earlier; every staged granule
// is covered by a counted wait + barrier before its first reader.
#define PH_BAR() do { asm volatile("" ::: "memory");                         \
                      __builtin_amdgcn_s_barrier();                          \
                      asm volatile("" ::: "memory"); } while(0)

#define VMCNT(n) asm volatile("s_waitcnt vmcnt(" #n ")" ::: "memory")

#define STG_A(db, half, j, kt)                                               \
  gl_lds16(gAw + (size_t)((half)*128 + (j)*64) * GK + (size_t)(kt)*64,       \
           sA + (db)*16384 + (half)*8192 + (j)*4096 + wave*512)

#define STG_B(db, half, j, kt)                                               \
  gl_lds16(gBw + (size_t)((half)*128 + (j)*64) * GK + (size_t)(kt)*64,       \
           sB + (db)*16384 + (half)*8192 + (j)*4096 + wave*512)

#define LOAD_A(db, mh)                                                       \
  _Pragma("unroll") for (int ks = 0; ks < 2; ++ks)                           \
    _Pragma("unroll") for (int mf = 0; mf < 4; ++mf)                         \
      af[ks][mf] = *(const short8*)(sA + (db)*16384 + aRowU + ((mh)*4+mf)*1024 + cswzU[ks]);

#define LOAD_B2(db, nh)                                                      \
  _Pragma("unroll") for (int ks = 0; ks < 2; ++ks)                           \
    _Pragma("unroll") for (int nf = 0; nf < 2; ++nf)                         \
      bf[ks][(nh)*2+nf] = *(const short8*)(sB + (db)*16384 + bRowU + ((nh)*2+nf)*1024 + cswzU[ks]);

#define MFMA_Q(mh, nh) do {                                                  \
  __builtin_amdgcn_s_setprio(1);                                             \
  _Pragma("unroll") for (int mf = 0; mf < 4; ++mf)                           \
    _Pragma("unroll") for (int nf = 0; nf < 2; ++nf) {                       \
      v4f t = acc[(mh)*4+mf][(nh)*2+nf];                                     \
      t = __builtin_amdgcn_mfma_f32_16x16x32_bf16(af[0][mf], bf[0][(nh)*2+nf], t, 0, 0, 0); \
      t = __builtin_amdgcn_mfma_f32_16x16x32_bf16(af[1][mf], bf[1][(nh)*2+nf], t, 0, 0, 0); \
      acc[(mh)*4+mf][(nh)*2+nf] = t;                                         \
    }                                                                        \
  __builtin_amdgcn_s_setprio(0);                                             \
} while (0)

__global__ __launch_bounds__(512, 2) void gemm256(const unsigned short* __restrict__ A,
                                                  const unsigned short* __restrict__ B,
                                                  void* __restrict__ Cp,
                                                  int ldc, int f32out){
  __shared__ __align__(16) unsigned short sA[2*16384];   // 64 KiB: [2][256][64]
  __shared__ __align__(16) unsigned short sB[2*16384];   // 64 KiB

  const int tid = threadIdx.x;
  const int wave = tid >> 6, lane = tid & 63;
  const int l15 = lane & 15, quad = lane >> 4;
  const int wm = wave >> 2, wn = wave & 3;
  const int m0 = blockIdx.y * 256, n0 = blockIdx.x * 256;

  // staging: per-lane pre-swizzled global source (LDS dst stays linear)
  const int lrow  = lane >> 3;                        // 8 rows per wave-KB
  const int lslot = (lane & 7) ^ lrow;                // swizzled 16B slot
  const size_t laneOff = (size_t)lrow * GK + (size_t)lslot * 8;
  const unsigned short* gAw = A + (size_t)(m0 + wave*8) * GK + laneOff;
  const unsigned short* gBw = B + (size_t)(n0 + wave*8) * GK + laneOff;

  // ds_read addressing (ushort units), swizzle col ^= (l15&7)<<4 bytes
  const int aRowU = (wm*128 + l15) * 64;
  const int bRowU = (wn*64  + l15) * 64;
  int cswzU[2];
  cswzU[0] = (( 0 + quad*16) ^ ((l15 & 7) << 4)) >> 1;
  cswzU[1] = ((64 + quad*16) ^ ((l15 & 7) << 4)) >> 1;

  v4f acc[8][4];
  #pragma unroll
  for (int i = 0; i < 8; i++)
    #pragma unroll
    for (int j = 0; j < 4; j++) acc[i][j] = (v4f){0.f,0.f,0.f,0.f};

  short8 af[2][4];   // A frags of current half-tile
  short8 bf[2][4];   // B frags: all four nf pairs of current tile

  // ---- prologue: A(0) full, B(0) full, B(1) full, A(1) j0-pair (14 loads) ----
  STG_A(0,0,0,0); STG_A(0,1,0,0); STG_A(0,0,1,0); STG_A(0,1,1,0);
  STG_B(0,0,0,0); STG_B(0,0,1,0); STG_B(0,1,0,0); STG_B(0,1,1,0);
  STG_B(1,0,0,1); STG_B(1,0,1,1); STG_B(1,1,0,1); STG_B(1,1,1,1);
  STG_A(1,0,0,1); STG_A(1,1,0,1);
  VMCNT(6);                      // A(0),B(0) landed; B(1)+A(1)j0 in flight
  PH_BAR();
  LOAD_B2(0,0);                  // bf01 of tile 0 ("prev-P8 trick" for i=0)

  #pragma unroll 1
  for (int i = 0; i < NIT-1; ++i){
    const int t1 = 2*i + 1, t2 = 2*i + 2, t3 = 2*i + 3;
    // P1: tile 2i quadrant (0,0); stage A(t1) j1-pair -> sA[buf1]
    LOAD_A(0,0);
    STG_A(1,0,1,t1); STG_A(1,1,1,t1);
    MFMA_Q(0,0);
    PH_BAR();
    // P2: quadrant (0,1)
    LOAD_B2(0,1);
    MFMA_Q(0,1);
    PH_BAR();
    // P3: quadrant (1,0); stage B(t2) j0-pair -> sB[buf0]; wait covers <=P8-prev
    LOAD_A(0,1);
    STG_B(0,0,0,t2); STG_B(0,1,0,t2);
    MFMA_Q(1,0);
    VMCNT(4);
    PH_BAR();
    // P4: quadrant (1,1); early-load bf01 of tile t1; stage B(t2) j1-pair
    LOAD_B2(1,0);
    STG_B(0,0,1,t2); STG_B(0,1,1,t2);
    MFMA_Q(1,1);
    PH_BAR();
    // P5: tile 2i+1 quadrant (0,0); stage A(t2) j0-pair -> sA[buf0]
    LOAD_A(1,0);
    STG_A(0,0,0,t2); STG_A(0,1,0,t2);
    MFMA_Q(0,0);
    PH_BAR();
    // P6: quadrant (0,1); stage A(t2) j1-pair; wait covers <=P4-this
    LOAD_B2(1,1);
    STG_A(0,0,1,t2); STG_A(0,1,1,t2);
    MFMA_Q(0,1);
    VMCNT(4);
    PH_BAR();
    // P7: quadrant (1,0); stage B(t3) all 4 -> sB[buf1]
    LOAD_A(1,1);
    STG_B(1,0,0,t3); STG_B(1,0,1,t3); STG_B(1,1,0,t3); STG_B(1,1,1,t3);
    MFMA_Q(1,0);
    PH_BAR();
    // P8: quadrant (1,1); early-load bf01 of tile t2; stage A(t3) j0-pair
    LOAD_B2(0,0);
    STG_A(1,0,0,t3); STG_A(1,1,0,t3);
    MFMA_Q(1,1);
    VMCNT(6);
    PH_BAR();
  }

  // ---- peeled last iteration (tiles NKT-2, NKT-1; no further stages) ----
  {
    const int t1 = NKT - 1;
    LOAD_A(0,0);
    STG_A(1,0,1,t1); STG_A(1,1,1,t1);   // j1-pair of the final tile
    MFMA_Q(0,0);
    PH_BAR();
    LOAD_B2(0,1);
    MFMA_Q(0,1);
    PH_BAR();
    LOAD_A(0,1);
    MFMA_Q(1,0);
    VMCNT(2);                            // covers A(t1) j0 (prev P8)
    PH_BAR();
    LOAD_B2(1,0);
    MFMA_Q(1,1);
    PH_BAR();
    LOAD_A(1,0);
    MFMA_Q(0,0);
    PH_BAR();
    LOAD_B2(1,1);
    MFMA_Q(0,1);
    VMCNT(0);                            // covers A(t1) j1 (P1 of this block)
    PH_BAR();
    LOAD_A(1,1);
    MFMA_Q(1,0);
    PH_BAR();
    MFMA_Q(1,1);
  }

  // ---- epilogue ----
  if (f32out){
    float* Cf = (float*)Cp;
    #pragma unroll
    for (int mf = 0; mf < 8; ++mf)
      #pragma unroll
      for (int r = 0; r < 4; ++r){
        const size_t row = (size_t)(m0 + wm*128 + mf*16 + quad*4 + r);
        float* crow = Cf + row * ldc + n0 + wn*64 + l15;
        #pragma unroll
        for (int nf = 0; nf < 4; ++nf) crow[nf*16] = acc[mf][nf][r];
      }
  } else {
    unsigned short* Cb = (unsigned short*)Cp;
    #pragma unroll
    for (int mf = 0; mf < 8; ++mf)
      #pragma unroll
      for (int r = 0; r < 4; ++r){
        const size_t row = (size_t)(m0 + wm*128 + mf*16 + quad*4 + r);
        unsigned short* crow = Cb + row * ldc + n0 + wn*64 + l15;
        #pragma unroll
        for (int nf = 0; nf < 4; ++nf) crow[nf*16] = f2bf(acc[mf][nf][r]);
      }
  }
}

// ---- RoPE on Q (PRE-SCALED by 1/sqrt(HD)*log2e): qkv -> qa[h][s][128] ----
__global__ __launch_bounds__(256) void rope_q_k(const unsigned short* __restrict__ qkv,
                                                unsigned short* __restrict__ qa){
  const int idx = blockIdx.x * 256 + threadIdx.x;
  const int j = idx & 63, h = (idx >> 6) & (H_-1), s = idx >> 11;
  const unsigned pair = *(const unsigned*)(qkv + (size_t)s*NQKV_ + h*HD_ + 2*j);
  const float x0 = bf2f((unsigned short)(pair & 0xffffu));
  const float x1 = bf2f((unsigned short)(pair >> 16));
  const float ang = (float)s * exp2f((float)j * NLOG2T_64);
  const float c = __cosf(ang), sn = __sinf(ang);
  const unsigned o = (unsigned)f2bf((x0*c - x1*sn) * SCALE_L2E)
                   | ((unsigned)f2bf((x0*sn + x1*c) * SCALE_L2E) << 16);
  *(unsigned*)(qa + ((size_t)h*S_ + s)*HD_ + 2*j) = o;
}

// ---------------- RoPE on K: qkv[s][4096+kv*128+..] -> ka[kv][s][128] ------------
__global__ __launch_bounds__(256) void rope_kk(const unsigned short* __restrict__ qkv,
                                               unsigned short* __restrict__ ka){
  const int idx = blockIdx.x * 256 + threadIdx.x;
  const int j = idx & 63, kv = (idx >> 6) & (KV_-1), s = idx >> 9;
  const unsigned pair = *(const unsigned*)(qkv + (size_t)s*NQKV_ + H_*HD_ + kv*HD_ + 2*j);
  const float x0 = bf2f((unsigned short)(pair & 0xffffu));
  const float x1 = bf2f((unsigned short)(pair >> 16));
  const float ang = (float)s * exp2f((float)j * NLOG2T_64);
  const float c = __cosf(ang), sn = __sinf(ang);
  const unsigned o = (unsigned)f2bf(x0*c - x1*sn) | ((unsigned)f2bf(x0*sn + x1*c) << 16);
  *(unsigned*)(ka + ((size_t)kv*S_ + s)*HD_ + 2*j) = o;
}

// ---------------- V transpose: qkv[s][5120+kv*128+d] -> vt[kv][d][s] -------------
__global__ __launch_bounds__(256) void vtrans_k(const unsigned short* __restrict__ qkv,
                                                unsigned short* __restrict__ vt){
  const int idx = blockIdx.x * 256 + threadIdx.x;
  const int s = idx & (S_-1), d = (idx >> 11) & (HD_-1), kv = idx >> 18;
  vt[idx] = qkv[(size_t)s*NQKV_ + (H_+KV_)*HD_ + kv*HD_ + d];
}

// ---------------- flash attention (causal, GQA), paired q-tiles ----------------
__device__ __forceinline__ void stage_kv(const unsigned short* __restrict__ ka,
                                         const unsigned short* __restrict__ vt,
                                         unsigned short* sKbuf, unsigned short* sVbuf,
                                         int hk, int t0, int wave, int lane){
  const int l15 = lane & 15, quad = lane >> 4;
  #pragma unroll
  for (int j = 0; j < 4; j++){
    const int c = wave*4 + j;                 // (kt,kk) = (c>>2, c&3)
    const int kt = c >> 2, kk = c & 3;
    gl_lds16(ka + (size_t)(hk*S_ + t0 + kt*16 + l15)*HD_ + kk*32 + quad*8,
             sKbuf + c*512);
  }
  #pragma unroll
  for (int j = 0; j < 4; j++){
    const int c = wave*4 + j;                 // (nt,kk2) = (c>>1, c&1)
    const int nt = c >> 1, kk2 = c & 1;
    gl_lds16(vt + (size_t)(hk*HD_ + nt*16 + l15)*S_ + t0 + kk2*32 + quad*8,
             sVbuf + c*512);
  }
}

__global__ __launch_bounds__(256, 2) void attn_k(const unsigned short* __restrict__ qa,
                                                 const unsigned short* __restrict__ ka,
                                                 const unsigned short* __restrict__ vt,
                                                 unsigned short* __restrict__ out){
  const int h = blockIdx.x, p = blockIdx.y;
  const int tid = threadIdx.x, wave = tid >> 6, lane = tid & 63;
  const int l15 = lane & 15, quad = lane >> 4;
  const int hk = h >> 2;                      // N_REP = 4
  const int nbB = 32 - p;                     // units for heavy tile (31-p)
  const int total = nbB + p + 1;              // 33 always

  __shared__ __align__(16) unsigned short sK[2][8192];   // 16KB x2
  __shared__ __align__(16) unsigned short sV[2][8192];   // 16KB x2
  __shared__ __align__(16) unsigned short sP[4][1024];   // 2KB per wave
  unsigned short* pl = &sP[wave][0];

  short8 ones;
  #pragma unroll
  for (int i = 0; i < 8; i++) ones[i] = (short)0x3F80;   // bf16 1.0

  int tile = 31 - p;
  short8 qf[4];
  {
    const unsigned short* qb = qa + (size_t)(h*S_ + tile*64 + wave*16 + l15)*HD_ + quad*8;
    #pragma unroll
    for (int kk = 0; kk < 4; kk++) qf[kk] = *(const short8*)(qb + kk*32);
  }

  v4f O[8];
  #pragma unroll
  for (int nt = 0; nt < 8; nt++) O[nt] = (v4f){0.f,0.f,0.f,0.f};
  float mrow[4], lrow[4];
  #pragma unroll
  for (int r = 0; r < 4; r++){ mrow[r] = -1e30f; lrow[r] = 0.f; }

  stage_kv(ka, vt, sK[0], sV[0], hk, 0, wave, lane);
  __syncthreads();

  for (int u = 0; u < total; ++u){
    const int cur = u & 1;
    if (u + 1 < total){
      const int b2 = (u + 1 < nbB) ? u + 1 : u + 1 - nbB;
      stage_kv(ka, vt, sK[cur^1], sV[cur^1], hk, b2*64, wave, lane);
    }

    // ---- QK^T: S[16 q-rows x 64 keys] ----
    const unsigned short* Kb = &sK[cur][0];
    v4f sc[4];
    #pragma unroll
    for (int kt = 0; kt < 4; kt++) sc[kt] = (v4f){0.f,0.f,0.f,0.f};
    #pragma unroll
    for (int kt = 0; kt < 4; kt++)
      #pragma unroll
      for (int kk = 0; kk < 4; kk++){
        const short8 kf = *(const short8*)(Kb + (kt*4 + kk)*512 + lane*8);
        sc[kt] = __builtin_amdgcn_mfma_f32_16x16x32_bf16(qf[kk], kf, sc[kt], 0, 0, 0);
      }

    // ---- online softmax (exp2 domain; Q pre-scaled) ----
    const bool diag = (u == nbB - 1) || (u == total - 1);   // wave-uniform
    float alpha[4];
    #pragma unroll
    for (int r = 0; r < 4; r++){
      float a0 = sc[0][r], a1 = sc[1][r], a2 = sc[2][r], a3 = sc[3][r];
      if (diag){
        const int rloc = wave*16 + quad*4 + r;
        if (     l15 > rloc) a0 = -1e30f;
        if (16 + l15 > rloc) a1 = -1e30f;
        if (32 + l15 > rloc) a2 = -1e30f;
        if (48 + l15 > rloc) a3 = -1e30f;
      }
      float mx = fmaxf(fmaxf(a0, a1), fmaxf(a2, a3));
      #pragma unroll
      for (int off = 1; off < 16; off <<= 1) mx = fmaxf(mx, __shfl_xor(mx, off, 16));
      const float mnew = fmaxf(mrow[r], mx);
      alpha[r] = exp2f(mrow[r] - mnew);
      mrow[r] = mnew;
      const float e0 = exp2f(a0 - mnew);
      const float e1 = exp2f(a1 - mnew);
      const float e2 = exp2f(a2 - mnew);
      const float e3 = exp2f(a3 - mnew);
      const int mr = (quad*4 + r)*8 + (l15 & 7);
      const int hi = (l15 >> 3) * 128;
      pl[      hi       + mr] = f2bf(e0);     // kt=0: kk2=0, q'=0..1
      pl[      hi + 256 + mr] = f2bf(e1);     // kt=1: kk2=0, q'=2..3
      pl[512 + hi       + mr] = f2bf(e2);     // kt=2: kk2=1, q'=0..1
      pl[512 + hi + 256 + mr] = f2bf(e3);     // kt=3: kk2=1, q'=2..3
    }
    #pragma unroll
    for (int nt = 0; nt < 8; nt++)
      #pragma unroll
      for (int r = 0; r < 4; r++) O[nt][r] *= alpha[r];

    __builtin_amdgcn_s_waitcnt(0xC07F);       // lgkmcnt(0): per-wave P region ready
    const short8 pf0 = *(const short8*)(pl + lane*8);
    const short8 pf1 = *(const short8*)(pl + 512 + lane*8);

    // ---- row-sum of P via ones-MFMA (every lane gets its row's sum) ----
    v4f rs = (v4f){0.f,0.f,0.f,0.f};
    rs = __builtin_amdgcn_mfma_f32_16x16x32_bf16(pf0, ones, rs, 0, 0, 0);
    rs = __builtin_amdgcn_mfma_f32_16x16x32_bf16(pf1, ones, rs, 0, 0, 0);

    // ---- PV: O[16 q-rows x 128 dims] ----
    const unsigned short* Vb = &sV[cur][0];
    #pragma unroll
    for (int nt = 0; nt < 8; nt++){
      const short8 vf0 = *(const short8*)(Vb + (nt*2    )*512 + lane*8);
      const short8 vf1 = *(const short8*)(Vb + (nt*2 + 1)*512 + lane*8);
      O[nt] = __builtin_amdgcn_mfma_f32_16x16x32_bf16(pf0, vf0, O[nt], 0, 0, 0);
      O[nt] = __builtin_amdgcn_mfma_f32_16x16x32_bf16(pf1, vf1, O[nt], 0, 0, 0);
    }
    #pragma unroll
    for (int r = 0; r < 4; r++) lrow[r] = lrow[r]*alpha[r] + rs[r];

    __syncthreads();   // all waves done with cur before it is overwritten

    if (u == nbB - 1){                        // finalize heavy tile, switch to light
      #pragma unroll
      for (int r = 0; r < 4; r++){
        const float inv = 1.0f / lrow[r];
        const size_t row = (size_t)(tile*64 + wave*16 + quad*4 + r);
        #pragma unroll
        for (int nt = 0; nt < 8; nt++)
          out[row*D_ + h*HD_ + nt*16 + l15] = f2bf(O[nt][r] * inv);
      }
      tile = p;
      const unsigned short* qb = qa + (size_t)(h*S_ + tile*64 + wave*16 + l15)*HD_ + quad*8;
      #pragma unroll
      for (int kk = 0; kk < 4; kk++) qf[kk] = *(const short8*)(qb + kk*32);
      #pragma unroll
      for (int nt = 0; nt < 8; nt++) O[nt] = (v4f){0.f,0.f,0.f,0.f};
      #pragma unroll
      for (int r = 0; r < 4; r++){ mrow[r] = -1e30f; lrow[r] = 0.f; }
    }
  }

  #pragma unroll
  for (int r = 0; r < 4; r++){
    const float inv = 1.0f / lrow[r];
    const size_t row = (size_t)(tile*64 + wave*16 + quad*4 + r);
    #pragma unroll
    for (int nt = 0; nt < 8; nt++)
      out[row*D_ + h*HD_ + nt*16 + l15] = f2bf(O[nt][r] * inv);
  }
}

// ---------------- launch ----------------
// Workspace map (MiB): [0,16) h_bf16 | [16,64) wqkv_bf16 (later: [16,48) wo_bf16,
// [48,64) attn_bf16) | [64,88) qkv_bf16 | [88,104) qa | [104,108) ka | [108,112) vt.
extern "C" void kernel_launch(void* const* d_in, const int* in_sizes, int n_in,
                              void* d_out, int out_size, void* d_ws, size_t ws_size,
                              hipStream_t stream){
  (void)in_sizes; (void)n_in; (void)out_size; (void)ws_size;
  const float* hidden = (const float*)d_in[0];
  const float* norm_w = (const float*)d_in[1];
  const float* wq = (const float*)d_in[2];
  const float* wk = (const float*)d_in[3];
  const float* wv = (const float*)d_in[4];
  const float* wo = (const float*)d_in[5];

  char* ws = (char*)d_ws;
  unsigned short* h_bf  = (unsigned short*)(ws);
  unsigned short* wqkv  = (unsigned short*)(ws + (size_t)(16u) * 1048576u);
  unsigned short* qkv   = (unsigned short*)(ws + (size_t)(64u) * 1048576u);
  unsigned short* qa    = (unsigned short*)(ws + (size_t)(88u) * 1048576u);
  unsigned short* ka    = (unsigned short*)(ws + (size_t)(104u) * 1048576u);
  unsigned short* vt    = (unsigned short*)(ws + (size_t)(108u) * 1048576u);
  unsigned short* wo_bf = (unsigned short*)(ws + (size_t)(16u) * 1048576u);  // reuse
  unsigned short* attnb = (unsigned short*)(ws + (size_t)(48u) * 1048576u);  // reuse

  rmsnorm_k<<<S_, 256, 0, stream>>>(hidden, norm_w, h_bf);

  cast_k<<<(D_*D_/4)/256, 256, 0, stream>>>(wq, wqkv, D_*D_/4);
  cast_k<<<(KV_*HD_*D_/4)/256, 256, 0, stream>>>(wk, wqkv + (size_t)H_*HD_*D_, KV_*HD_*D_/4);
  cast_k<<<(KV_*HD_*D_/4)/256, 256, 0, stream>>>(wv, wqkv + (size_t)(H_+KV_)*HD_*D_, KV_*HD_*D_/4);

  gemm256<<<dim3(NQKV_/256, S_/256), 512, 0, stream>>>(h_bf, wqkv, qkv, NQKV_, 0);

  rope_q_k<<<(S_*H_*64)/256, 256, 0, stream>>>(qkv, qa);
  rope_kk <<<(S_*KV_*64)/256, 256, 0, stream>>>(qkv, ka);
  vtrans_k<<<(KV_*HD_*S_)/256, 256, 0, stream>>>(qkv, vt);

  cast_k<<<(D_*D_/4)/256, 256, 0, stream>>>(wo, wo_bf, D_*D_/4);

  attn_k<<<dim3(H_, 16), 256, 0, stream>>>(qa, ka, vt, attnb);

  gemm256<<<dim3(D_/256, S_/256), 512, 0, stream>>>(attnb, wo_bf, d_out, D_, 1);
}

// Round 3
// 544.232 us; speedup vs baseline: 1.0349x; 1.0006x over previous
//
#include <hip/hip_runtime.h>
#include <stdint.h>
#include <stddef.h>

#define AS1 __attribute__((address_space(1)))
#define AS3 __attribute__((address_space(3)))

typedef short short8 __attribute__((ext_vector_type(8)));   // 8 bf16 (4 VGPRs)
typedef float v4f    __attribute__((ext_vector_type(4)));   // MFMA C/D frag
typedef unsigned short us4 __attribute__((ext_vector_type(4)));

constexpr int S_  = 2048;
constexpr int D_  = 4096;
constexpr int H_  = 32;
constexpr int KV_ = 8;
constexpr int HD_ = 128;
constexpr int NQKV_ = H_*HD_ + 2*KV_*HD_;   // 6144
constexpr float SCALE_L2E = 0.12751744154070513f;  // (1/sqrt(128)) * log2(e)
constexpr float NLOG2T_64 = -0.24390063241307518f; // -log2(50000)/64

// 256x256 8-phase GEMM geometry (both GEMMs have K = 4096)
constexpr int GK  = 4096;
constexpr int NKT = GK / 64;   // 64 K-tiles of 64
constexpr int NIT = NKT / 2;   // 32 iterations (2 K-tiles / iter)

__device__ __forceinline__ unsigned short f2bf(float f){
  union { float f; unsigned u; } v; v.f = f;
  unsigned r = v.u + 0x7FFFu + ((v.u >> 16) & 1u);     // RNE
  return (unsigned short)(r >> 16);
}
__device__ __forceinline__ float bf2f(unsigned short h){
  union { unsigned u; float f; } v; v.u = ((unsigned)h) << 16; return v.f;
}

// async global->LDS, 16B per lane; LDS dst = wave-uniform base + lane*16
__device__ __forceinline__ void gl_lds16(const unsigned short* g, unsigned short* l){
  __builtin_amdgcn_global_load_lds((AS1 unsigned int*)(uintptr_t)g,
                                   (AS3 unsigned int*)l, 16, 0, 0);
}

// ---------------- RMSNorm: hidden fp32 [S][D] -> h bf16 [S][D] ----------------
__global__ __launch_bounds__(256) void rmsnorm_k(const float* __restrict__ hidden,
                                                 const float* __restrict__ w,
                                                 unsigned short* __restrict__ out){
  const int s = blockIdx.x, tid = threadIdx.x;
  const float4* row = (const float4*)(hidden + (size_t)s * D_);
  float4 v[4];
  float ss = 0.f;
  #pragma unroll
  for (int i = 0; i < 4; i++){
    float4 t = row[tid + 256*i]; v[i] = t;
    ss += t.x*t.x + t.y*t.y + t.z*t.z + t.w*t.w;
  }
  #pragma unroll
  for (int off = 32; off >= 1; off >>= 1) ss += __shfl_xor(ss, off, 64);
  __shared__ float wsum[4];
  if ((tid & 63) == 0) wsum[tid >> 6] = ss;
  __syncthreads();
  const float total = wsum[0] + wsum[1] + wsum[2] + wsum[3];
  const float r = rsqrtf(total * (1.0f / D_) + 1e-6f);
  const float4* w4 = (const float4*)w;
  us4* o = (us4*)(out + (size_t)s * D_);
  #pragma unroll
  for (int i = 0; i < 4; i++){
    float4 t = v[i], ww = w4[tid + 256*i];
    us4 p;
    p[0] = f2bf(t.x * r * ww.x); p[1] = f2bf(t.y * r * ww.y);
    p[2] = f2bf(t.z * r * ww.z); p[3] = f2bf(t.w * r * ww.w);
    o[tid + 256*i] = p;
  }
}

// ---------------- fp32 -> bf16 cast ----------------
__global__ __launch_bounds__(256) void cast_k(const float* __restrict__ src,
                                              unsigned short* __restrict__ dst, int n4){
  const int i = blockIdx.x * 256 + threadIdx.x;
  if (i >= n4) return;
  float4 t = ((const float4*)src)[i];
  us4 p;
  p[0] = f2bf(t.x); p[1] = f2bf(t.y); p[2] = f2bf(t.z); p[3] = f2bf(t.w);
  ((us4*)dst)[i] = p;
}

// ---------------- 256x256 8-phase bt-GEMM: C[M,N] = A[M,K]*B[N,K]^T ------------
// 512 threads = 8 waves (2M x 4N). BK=64, 2 K-tiles per iteration, 8 phases,
// one barrier per phase; counted vmcnt(4)@P3, vmcnt(4)@P6, vmcnt(6)@P8.
// T1: 2D-chunked bijective XCD swizzle. Linear block id i -> XCD g=i&7 owns a
// contiguous (bw x bh) sub-grid of block-tiles, so co-XCD blocks share A/B
// panels in their XCD's private 4MiB L2. Per-iteration working set per XCD
// = (bw+bh)*64KB << 4MiB. Requires gridDim.x%bw==0, gridDim.y%bh==0,
// (gridDim.x/bw)*(gridDim.y/bh)==8. QKV: 24x8 grid, bw=6,bh=4. WO: 16x8, 4x4.
#define PH_BAR() do { asm volatile("" ::: "memory");                         \
                      __builtin_amdgcn_s_barrier();                          \
                      asm volatile("" ::: "memory"); } while(0)

#define VMCNT(n) asm volatile("s_waitcnt vmcnt(" #n ")" ::: "memory")

#define STG_A(db, half, j, kt)                                               \
  gl_lds16(gAw + (size_t)((half)*128 + (j)*64) * GK + (size_t)(kt)*64,       \
           sA + (db)*16384 + (half)*8192 + (j)*4096 + wave*512)

#define STG_B(db, half, j, kt)                                               \
  gl_lds16(gBw + (size_t)((half)*128 + (j)*64) * GK + (size_t)(kt)*64,       \
           sB + (db)*16384 + (half)*8192 + (j)*4096 + wave*512)

#define LOAD_A(db, mh)                                                       \
  _Pragma("unroll") for (int ks = 0; ks < 2; ++ks)                           \
    _Pragma("unroll") for (int mf = 0; mf < 4; ++mf)                         \
      af[ks][mf] = *(const short8*)(sA + (db)*16384 + aRowU + ((mh)*4+mf)*1024 + cswzU[ks]);

#define LOAD_B2(db, nh)                                                      \
  _Pragma("unroll") for (int ks = 0; ks < 2; ++ks)                           \
    _Pragma("unroll") for (int nf = 0; nf < 2; ++nf)                         \
      bf[ks][(nh)*2+nf] = *(const short8*)(sB + (db)*16384 + bRowU + ((nh)*2+nf)*1024 + cswzU[ks]);

#define MFMA_Q(mh, nh) do {                                                  \
  __builtin_amdgcn_s_setprio(1);                                             \
  _Pragma("unroll") for (int mf = 0; mf < 4; ++mf)                           \
    _Pragma("unroll") for (int nf = 0; nf < 2; ++nf) {                       \
      v4f t = acc[(mh)*4+mf][(nh)*2+nf];                                     \
      t = __builtin_amdgcn_mfma_f32_16x16x32_bf16(af[0][mf], bf[0][(nh)*2+nf], t, 0, 0, 0); \
      t = __builtin_amdgcn_mfma_f32_16x16x32_bf16(af[1][mf], bf[1][(nh)*2+nf], t, 0, 0, 0); \
      acc[(mh)*4+mf][(nh)*2+nf] = t;                                         \
    }                                                                        \
  __builtin_amdgcn_s_setprio(0);                                             \
} while (0)

__global__ __launch_bounds__(512, 2) void gemm256(const unsigned short* __restrict__ A,
                                                  const unsigned short* __restrict__ B,
                                                  void* __restrict__ Cp,
                                                  int ldc, int f32out,
                                                  int bw, int bh){
  __shared__ __align__(16) unsigned short sA[2*16384];   // 64 KiB: [2][256][64]
  __shared__ __align__(16) unsigned short sB[2*16384];   // 64 KiB

  const int tid = threadIdx.x;
  const int wave = tid >> 6, lane = tid & 63;
  const int l15 = lane & 15, quad = lane >> 4;
  const int wm = wave >> 2, wn = wave & 3;

  // T1: 2D-chunked XCD swizzle (bijective: bw*bh blocks per XCD)
  const unsigned lin = blockIdx.y * gridDim.x + blockIdx.x;
  const unsigned g = lin & 7u, j = lin >> 3;
  const unsigned cpr = gridDim.x / (unsigned)bw;     // chunks per chunk-row
  const unsigned cx = g % cpr, cy = g / cpr;
  const unsigned lx = j % (unsigned)bw, ly = j / (unsigned)bw;
  const int m0 = (int)(cy * bh + ly) * 256;
  const int n0 = (int)(cx * bw + lx) * 256;

  // staging: per-lane pre-swizzled global source (LDS dst stays linear)
  const int lrow  = lane >> 3;                        // 8 rows per wave-KB
  const int lslot = (lane & 7) ^ lrow;                // swizzled 16B slot
  const size_t laneOff = (size_t)lrow * GK + (size_t)lslot * 8;
  const unsigned short* gAw = A + (size_t)(m0 + wave*8) * GK + laneOff;
  const unsigned short* gBw = B + (size_t)(n0 + wave*8) * GK + laneOff;

  // ds_read addressing (ushort units), swizzle col ^= (l15&7)<<4 bytes
  const int aRowU = (wm*128 + l15) * 64;
  const int bRowU = (wn*64  + l15) * 64;
  int cswzU[2];
  cswzU[0] = (( 0 + quad*16) ^ ((l15 & 7) << 4)) >> 1;
  cswzU[1] = ((64 + quad*16) ^ ((l15 & 7) << 4)) >> 1;

  v4f acc[8][4];
  #pragma unroll
  for (int i = 0; i < 8; i++)
    #pragma unroll
    for (int j2 = 0; j2 < 4; j2++) acc[i][j2] = (v4f){0.f,0.f,0.f,0.f};

  short8 af[2][4];   // A frags of current half-tile
  short8 bf[2][4];   // B frags: all four nf pairs of current tile

  // ---- prologue: A(0) full, B(0) full, B(1) full, A(1) j0-pair (14 loads) ----
  STG_A(0,0,0,0); STG_A(0,1,0,0); STG_A(0,0,1,0); STG_A(0,1,1,0);
  STG_B(0,0,0,0); STG_B(0,0,1,0); STG_B(0,1,0,0); STG_B(0,1,1,0);
  STG_B(1,0,0,1); STG_B(1,0,1,1); STG_B(1,1,0,1); STG_B(1,1,1,1);
  STG_A(1,0,0,1); STG_A(1,1,0,1);
  VMCNT(6);                      // A(0),B(0) landed; B(1)+A(1)j0 in flight
  PH_BAR();
  LOAD_B2(0,0);                  // bf01 of tile 0 ("prev-P8 trick" for i=0)

  #pragma unroll 1
  for (int i = 0; i < NIT-1; ++i){
    const int t1 = 2*i + 1, t2 = 2*i + 2, t3 = 2*i + 3;
    // P1: tile 2i quadrant (0,0); stage A(t1) j1-pair -> sA[buf1]
    LOAD_A(0,0);
    STG_A(1,0,1,t1); STG_A(1,1,1,t1);
    MFMA_Q(0,0);
    PH_BAR();
    // P2: quadrant (0,1)
    LOAD_B2(0,1);
    MFMA_Q(0,1);
    PH_BAR();
    // P3: quadrant (1,0); stage B(t2) j0-pair -> sB[buf0]; wait covers <=P8-prev
    LOAD_A(0,1);
    STG_B(0,0,0,t2); STG_B(0,1,0,t2);
    MFMA_Q(1,0);
    VMCNT(4);
    PH_BAR();
    // P4: quadrant (1,1); early-load bf01 of tile t1; stage B(t2) j1-pair
    LOAD_B2(1,0);
    STG_B(0,0,1,t2); STG_B(0,1,1,t2);
    MFMA_Q(1,1);
    PH_BAR();
    // P5: tile 2i+1 quadrant (0,0); stage A(t2) j0-pair -> sA[buf0]
    LOAD_A(1,0);
    STG_A(0,0,0,t2); STG_A(0,1,0,t2);
    MFMA_Q(0,0);
    PH_BAR();
    // P6: quadrant (0,1); stage A(t2) j1-pair; wait covers <=P4-this
    LOAD_B2(1,1);
    STG_A(0,0,1,t2); STG_A(0,1,1,t2);
    MFMA_Q(0,1);
    VMCNT(4);
    PH_BAR();
    // P7: quadrant (1,0); stage B(t3) all 4 -> sB[buf1]
    LOAD_A(1,1);
    STG_B(1,0,0,t3); STG_B(1,0,1,t3); STG_B(1,1,0,t3); STG_B(1,1,1,t3);
    MFMA_Q(1,0);
    PH_BAR();
    // P8: quadrant (1,1); early-load bf01 of tile t2; stage A(t3) j0-pair
    LOAD_B2(0,0);
    STG_A(1,0,0,t3); STG_A(1,1,0,t3);
    MFMA_Q(1,1);
    VMCNT(6);
    PH_BAR();
  }

  // ---- peeled last iteration (tiles NKT-2, NKT-1; no further stages) ----
  {
    const int t1 = NKT - 1;
    LOAD_A(0,0);
    STG_A(1,0,1,t1); STG_A(1,1,1,t1);   // j1-pair of the final tile
    MFMA_Q(0,0);
    PH_BAR();
    LOAD_B2(0,1);
    MFMA_Q(0,1);
    PH_BAR();
    LOAD_A(0,1);
    MFMA_Q(1,0);
    VMCNT(2);                            // covers A(t1) j0 (prev P8)
    PH_BAR();
    LOAD_B2(1,0);
    MFMA_Q(1,1);
    PH_BAR();
    LOAD_A(1,0);
    MFMA_Q(0,0);
    PH_BAR();
    LOAD_B2(1,1);
    MFMA_Q(0,1);
    VMCNT(0);                            // covers A(t1) j1 (P1 of this block)
    PH_BAR();
    LOAD_A(1,1);
    MFMA_Q(1,0);
    PH_BAR();
    MFMA_Q(1,1);
  }

  // ---- epilogue ----
  if (f32out){
    float* Cf = (float*)Cp;
    #pragma unroll
    for (int mf = 0; mf < 8; ++mf)
      #pragma unroll
      for (int r = 0; r < 4; ++r){
        const size_t row = (size_t)(m0 + wm*128 + mf*16 + quad*4 + r);
        float* crow = Cf + row * ldc + n0 + wn*64 + l15;
        #pragma unroll
        for (int nf = 0; nf < 4; ++nf) crow[nf*16] = acc[mf][nf][r];
      }
  } else {
    unsigned short* Cb = (unsigned short*)Cp;
    #pragma unroll
    for (int mf = 0; mf < 8; ++mf)
      #pragma unroll
      for (int r = 0; r < 4; ++r){
        const size_t row = (size_t)(m0 + wm*128 + mf*16 + quad*4 + r);
        unsigned short* crow = Cb + row * ldc + n0 + wn*64 + l15;
        #pragma unroll
        for (int nf = 0; nf < 4; ++nf) crow[nf*16] = f2bf(acc[mf][nf][r]);
      }
  }
}

// ---- RoPE on Q (PRE-SCALED by 1/sqrt(HD)*log2e): qkv -> qa[h][s][128] ----
__global__ __launch_bounds__(256) void rope_q_k(const unsigned short* __restrict__ qkv,
                                                unsigned short* __restrict__ qa){
  const int idx = blockIdx.x * 256 + threadIdx.x;
  const int j = idx & 63, h = (idx >> 6) & (H_-1), s = idx >> 11;
  const unsigned pair = *(const unsigned*)(qkv + (size_t)s*NQKV_ + h*HD_ + 2*j);
  const float x0 = bf2f((unsigned short)(pair & 0xffffu));
  const float x1 = bf2f((unsigned short)(pair >> 16));
  const float ang = (float)s * exp2f((float)j * NLOG2T_64);
  const float c = __cosf(ang), sn = __sinf(ang);
  const unsigned o = (unsigned)f2bf((x0*c - x1*sn) * SCALE_L2E)
                   | ((unsigned)f2bf((x0*sn + x1*c) * SCALE_L2E) << 16);
  *(unsigned*)(qa + ((size_t)h*S_ + s)*HD_ + 2*j) = o;
}

// ---------------- RoPE on K: qkv[s][4096+kv*128+..] -> ka[kv][s][128] ------------
__global__ __launch_bounds__(256) void rope_kk(const unsigned short* __restrict__ qkv,
                                               unsigned short* __restrict__ ka){
  const int idx = blockIdx.x * 256 + threadIdx.x;
  const int j = idx & 63, kv = (idx >> 6) & (KV_-1), s = idx >> 9;
  const unsigned pair = *(const unsigned*)(qkv + (size_t)s*NQKV_ + H_*HD_ + kv*HD_ + 2*j);
  const float x0 = bf2f((unsigned short)(pair & 0xffffu));
  const float x1 = bf2f((unsigned short)(pair >> 16));
  const float ang = (float)s * exp2f((float)j * NLOG2T_64);
  const float c = __cosf(ang), sn = __sinf(ang);
  const unsigned o = (unsigned)f2bf(x0*c - x1*sn) | ((unsigned)f2bf(x0*sn + x1*c) << 16);
  *(unsigned*)(ka + ((size_t)kv*S_ + s)*HD_ + 2*j) = o;
}

// ---------------- V transpose: qkv[s][5120+kv*128+d] -> vt[kv][d][s] -------------
__global__ __launch_bounds__(256) void vtrans_k(const unsigned short* __restrict__ qkv,
                                                unsigned short* __restrict__ vt){
  const int idx = blockIdx.x * 256 + threadIdx.x;
  const int s = idx & (S_-1), d = (idx >> 11) & (HD_-1), kv = idx >> 18;
  vt[idx] = qkv[(size_t)s*NQKV_ + (H_+KV_)*HD_ + kv*HD_ + d];
}

// ---------------- flash attention (causal, GQA), paired q-tiles ----------------
__device__ __forceinline__ void stage_kv(const unsigned short* __restrict__ ka,
                                         const unsigned short* __restrict__ vt,
                                         unsigned short* sKbuf, unsigned short* sVbuf,
                                         int hk, int t0, int wave, int lane){
  const int l15 = lane & 15, quad = lane >> 4;
  #pragma unroll
  for (int j = 0; j < 4; j++){
    const int c = wave*4 + j;                 // (kt,kk) = (c>>2, c&3)
    const int kt = c >> 2, kk = c & 3;
    gl_lds16(ka + (size_t)(hk*S_ + t0 + kt*16 + l15)*HD_ + kk*32 + quad*8,
             sKbuf + c*512);
  }
  #pragma unroll
  for (int j = 0; j < 4; j++){
    const int c = wave*4 + j;                 // (nt,kk2) = (c>>1, c&1)
    const int nt = c >> 1, kk2 = c & 1;
    gl_lds16(vt + (size_t)(hk*HD_ + nt*16 + l15)*S_ + t0 + kk2*32 + quad*8,
             sVbuf + c*512);
  }
}

__global__ __launch_bounds__(256, 2) void attn_k(const unsigned short* __restrict__ qa,
                                                 const unsigned short* __restrict__ ka,
                                                 const unsigned short* __restrict__ vt,
                                                 unsigned short* __restrict__ out){
  const int h = blockIdx.x, p = blockIdx.y;
  const int tid = threadIdx.x, wave = tid >> 6, lane = tid & 63;
  const int l15 = lane & 15, quad = lane >> 4;
  const int hk = h >> 2;                      // N_REP = 4
  const int nbB = 32 - p;                     // units for heavy tile (31-p)
  const int total = nbB + p + 1;              // 33 always

  __shared__ __align__(16) unsigned short sK[2][8192];   // 16KB x2
  __shared__ __align__(16) unsigned short sV[2][8192];   // 16KB x2
  __shared__ __align__(16) unsigned short sP[4][1024];   // 2KB per wave
  unsigned short* pl = &sP[wave][0];

  short8 ones;
  #pragma unroll
  for (int i = 0; i < 8; i++) ones[i] = (short)0x3F80;   // bf16 1.0

  int tile = 31 - p;
  short8 qf[4];
  {
    const unsigned short* qb = qa + (size_t)(h*S_ + tile*64 + wave*16 + l15)*HD_ + quad*8;
    #pragma unroll
    for (int kk = 0; kk < 4; kk++) qf[kk] = *(const short8*)(qb + kk*32);
  }

  v4f O[8];
  #pragma unroll
  for (int nt = 0; nt < 8; nt++) O[nt] = (v4f){0.f,0.f,0.f,0.f};
  float mrow[4], lrow[4];
  #pragma unroll
  for (int r = 0; r < 4; r++){ mrow[r] = -1e30f; lrow[r] = 0.f; }

  stage_kv(ka, vt, sK[0], sV[0], hk, 0, wave, lane);
  __syncthreads();

  for (int u = 0; u < total; ++u){
    const int cur = u & 1;
    if (u + 1 < total){
      const int b2 = (u + 1 < nbB) ? u + 1 : u + 1 - nbB;
      stage_kv(ka, vt, sK[cur^1], sV[cur^1], hk, b2*64, wave, lane);
    }

    // ---- QK^T: S[16 q-rows x 64 keys] ----
    const unsigned short* Kb = &sK[cur][0];
    v4f sc[4];
    #pragma unroll
    for (int kt = 0; kt < 4; kt++) sc[kt] = (v4f){0.f,0.f,0.f,0.f};
    #pragma unroll
    for (int kt = 0; kt < 4; kt++)
      #pragma unroll
      for (int kk = 0; kk < 4; kk++){
        const short8 kf = *(const short8*)(Kb + (kt*4 + kk)*512 + lane*8);
        sc[kt] = __builtin_amdgcn_mfma_f32_16x16x32_bf16(qf[kk], kf, sc[kt], 0, 0, 0);
      }

    // ---- online softmax (exp2 domain; Q pre-scaled) ----
    const bool diag = (u == nbB - 1) || (u == total - 1);   // wave-uniform
    float alpha[4];
    #pragma unroll
    for (int r = 0; r < 4; r++){
      float a0 = sc[0][r], a1 = sc[1][r], a2 = sc[2][r], a3 = sc[3][r];
      if (diag){
        const int rloc = wave*16 + quad*4 + r;
        if (     l15 > rloc) a0 = -1e30f;
        if (16 + l15 > rloc) a1 = -1e30f;
        if (32 + l15 > rloc) a2 = -1e30f;
        if (48 + l15 > rloc) a3 = -1e30f;
      }
      float mx = fmaxf(fmaxf(a0, a1), fmaxf(a2, a3));
      #pragma unroll
      for (int off = 1; off < 16; off <<= 1) mx = fmaxf(mx, __shfl_xor(mx, off, 16));
      const float mnew = fmaxf(mrow[r], mx);
      alpha[r] = exp2f(mrow[r] - mnew);
      mrow[r] = mnew;
      const float e0 = exp2f(a0 - mnew);
      const float e1 = exp2f(a1 - mnew);
      const float e2 = exp2f(a2 - mnew);
      const float e3 = exp2f(a3 - mnew);
      const int mr = (quad*4 + r)*8 + (l15 & 7);
      const int hi = (l15 >> 3) * 128;
      pl[      hi       + mr] = f2bf(e0);     // kt=0: kk2=0, q'=0..1
      pl[      hi + 256 + mr] = f2bf(e1);     // kt=1: kk2=0, q'=2..3
      pl[512 + hi       + mr] = f2bf(e2);     // kt=2: kk2=1, q'=0..1
      pl[512 + hi + 256 + mr] = f2bf(e3);     // kt=3: kk2=1, q'=2..3
    }
    #pragma unroll
    for (int nt = 0; nt < 8; nt++)
      #pragma unroll
      for (int r = 0; r < 4; r++) O[nt][r] *= alpha[r];

    __builtin_amdgcn_s_waitcnt(0xC07F);       // lgkmcnt(0): per-wave P region ready
    const short8 pf0 = *(const short8*)(pl + lane*8);
    const short8 pf1 = *(const short8*)(pl + 512 + lane*8);

    // ---- row-sum of P via ones-MFMA (every lane gets its row's sum) ----
    v4f rs = (v4f){0.f,0.f,0.f,0.f};
    rs = __builtin_amdgcn_mfma_f32_16x16x32_bf16(pf0, ones, rs, 0, 0, 0);
    rs = __builtin_amdgcn_mfma_f32_16x16x32_bf16(pf1, ones, rs, 0, 0, 0);

    // ---- PV: O[16 q-rows x 128 dims] ----
    const unsigned short* Vb = &sV[cur][0];
    #pragma unroll
    for (int nt = 0; nt < 8; nt++){
      const short8 vf0 = *(const short8*)(Vb + (nt*2    )*512 + lane*8);
      const short8 vf1 = *(const short8*)(Vb + (nt*2 + 1)*512 + lane*8);
      O[nt] = __builtin_amdgcn_mfma_f32_16x16x32_bf16(pf0, vf0, O[nt], 0, 0, 0);
      O[nt] = __builtin_amdgcn_mfma_f32_16x16x32_bf16(pf1, vf1, O[nt], 0, 0, 0);
    }
    #pragma unroll
    for (int r = 0; r < 4; r++) lrow[r] = lrow[r]*alpha[r] + rs[r];

    __syncthreads();   // all waves done with cur before it is overwritten

    if (u == nbB - 1){                        // finalize heavy tile, switch to light
      #pragma unroll
      for (int r = 0; r < 4; r++){
        const float inv = 1.0f / lrow[r];
        const size_t row = (size_t)(tile*64 + wave*16 + quad*4 + r);
        #pragma unroll
        for (int nt = 0; nt < 8; nt++)
          out[row*D_ + h*HD_ + nt*16 + l15] = f2bf(O[nt][r] * inv);
      }
      tile = p;
      const unsigned short* qb = qa + (size_t)(h*S_ + tile*64 + wave*16 + l15)*HD_ + quad*8;
      #pragma unroll
      for (int kk = 0; kk < 4; kk++) qf[kk] = *(const short8*)(qb + kk*32);
      #pragma unroll
      for (int nt = 0; nt < 8; nt++) O[nt] = (v4f){0.f,0.f,0.f,0.f};
      #pragma unroll
      for (int r = 0; r < 4; r++){ mrow[r] = -1e30f; lrow[r] = 0.f; }
    }
  }

  #pragma unroll
  for (int r = 0; r < 4; r++){
    const float inv = 1.0f / lrow[r];
    const size_t row = (size_t)(tile*64 + wave*16 + quad*4 + r);
    #pragma unroll
    for (int nt = 0; nt < 8; nt++)
      out[row*D_ + h*HD_ + nt*16 + l15] = f2bf(O[nt][r] * inv);
  }
}

// ---------------- launch ----------------
// Workspace map (MiB): [0,16) h_bf16 | [16,64) wqkv_bf16 (later: [16,48) wo_bf16,
// [48,64) attn_bf16) | [64,88) qkv_bf16 | [88,104) qa | [104,108) ka | [108,112) vt.
extern "C" void kernel_launch(void* const* d_in, const int* in_sizes, int n_in,
                              void* d_out, int out_size, void* d_ws, size_t ws_size,
                              hipStream_t stream){
  (void)in_sizes; (void)n_in; (void)out_size; (void)ws_size;
  const float* hidden = (const float*)d_in[0];
  const float* norm_w = (const float*)d_in[1];
  const float* wq = (const float*)d_in[2];
  const float* wk = (const float*)d_in[3];
  const float* wv = (const float*)d_in[4];
  const float* wo = (const float*)d_in[5];

  char* ws = (char*)d_ws;
  unsigned short* h_bf  = (unsigned short*)(ws);
  unsigned short* wqkv  = (unsigned short*)(ws + (size_t)(16u) * 1048576u);
  unsigned short* qkv   = (unsigned short*)(ws + (size_t)(64u) * 1048576u);
  unsigned short* qa    = (unsigned short*)(ws + (size_t)(88u) * 1048576u);
  unsigned short* ka    = (unsigned short*)(ws + (size_t)(104u) * 1048576u);
  unsigned short* vt    = (unsigned short*)(ws + (size_t)(108u) * 1048576u);
  unsigned short* wo_bf = (unsigned short*)(ws + (size_t)(16u) * 1048576u);  // reuse
  unsigned short* attnb = (unsigned short*)(ws + (size_t)(48u) * 1048576u);  // reuse

  rmsnorm_k<<<S_, 256, 0, stream>>>(hidden, norm_w, h_bf);

  cast_k<<<(D_*D_/4)/256, 256, 0, stream>>>(wq, wqkv, D_*D_/4);
  cast_k<<<(KV_*HD_*D_/4)/256, 256, 0, stream>>>(wk, wqkv + (size_t)H_*HD_*D_, KV_*HD_*D_/4);
  cast_k<<<(KV_*HD_*D_/4)/256, 256, 0, stream>>>(wv, wqkv + (size_t)(H_+KV_)*HD_*D_, KV_*HD_*D_/4);

  // QKV GEMM: grid 24x8 blocks; XCD chunks of 6x4
  gemm256<<<dim3(NQKV_/256, S_/256), 512, 0, stream>>>(h_bf, wqkv, qkv, NQKV_, 0, 6, 4);

  rope_q_k<<<(S_*H_*64)/256, 256, 0, stream>>>(qkv, qa);
  rope_kk <<<(S_*KV_*64)/256, 256, 0, stream>>>(qkv, ka);
  vtrans_k<<<(KV_*HD_*S_)/256, 256, 0, stream>>>(qkv, vt);

  cast_k<<<(D_*D_/4)/256, 256, 0, stream>>>(wo, wo_bf, D_*D_/4);

  attn_k<<<dim3(H_, 16), 256, 0, stream>>>(qa, ka, vt, attnb);

  // WO GEMM: grid 16x8 blocks; XCD chunks of 4x4
  gemm256<<<dim3(D_/256, S_/256), 512, 0, stream>>>(attnb, wo_bf, d_out, D_, 1, 4, 4);
}

// Round 8
// 469.244 us; speedup vs baseline: 1.2003x; 1.1598x over previous
//
#include <hip/hip_runtime.h>
#include <stdint.h>
#include <stddef.h>

#define AS1 __attribute__((address_space(1)))
#define AS3 __attribute__((address_space(3)))

typedef short short8 __attribute__((ext_vector_type(8)));   // 8 bf16 (4 VGPRs)
typedef float v4f    __attribute__((ext_vector_type(4)));   // MFMA C/D frag
typedef unsigned short us4 __attribute__((ext_vector_type(4)));

constexpr int S_  = 2048;
constexpr int D_  = 4096;
constexpr int H_  = 32;
constexpr int KV_ = 8;
constexpr int HD_ = 128;
constexpr int NQKV_ = H_*HD_ + 2*KV_*HD_;   // 6144
constexpr float SCALE_L2E = 0.12751744154070513f;  // (1/sqrt(128)) * log2(e)
constexpr float NLOG2T_64 = -0.24390063241307518f; // -log2(50000)/64

constexpr int GK  = 4096;
constexpr int NKT = GK / 64;   // 64 K-tiles of 64
constexpr int NIT = NKT / 2;   // 32 iterations (2 K-tiles / iter)

__device__ __forceinline__ unsigned short f2bf(float f){
  union { float f; unsigned u; } v; v.f = f;
  unsigned r = v.u + 0x7FFFu + ((v.u >> 16) & 1u);     // RNE
  return (unsigned short)(r >> 16);
}
__device__ __forceinline__ float bf2f(unsigned short h){
  union { unsigned u; float f; } v; v.u = ((unsigned)h) << 16; return v.f;
}

// async global->LDS, 16B per lane; LDS dst = wave-uniform base + lane*16
__device__ __forceinline__ void gl_lds16(const unsigned short* g, unsigned short* l){
  __builtin_amdgcn_global_load_lds((AS1 unsigned int*)(uintptr_t)g,
                                   (AS3 unsigned int*)l, 16, 0, 0);
}

// ---------------- RMSNorm: hidden fp32 [S][D] -> h bf16 [S][D] ----------------
__global__ __launch_bounds__(256) void rmsnorm_k(const float* __restrict__ hidden,
                                                 const float* __restrict__ w,
                                                 unsigned short* __restrict__ out){
  const int s = blockIdx.x, tid = threadIdx.x;
  const float4* row = (const float4*)(hidden + (size_t)s * D_);
  float4 v[4];
  float ss = 0.f;
  #pragma unroll
  for (int i = 0; i < 4; i++){
    float4 t = row[tid + 256*i]; v[i] = t;
    ss += t.x*t.x + t.y*t.y + t.z*t.z + t.w*t.w;
  }
  #pragma unroll
  for (int off = 32; off >= 1; off >>= 1) ss += __shfl_xor(ss, off, 64);
  __shared__ float wsum[4];
  if ((tid & 63) == 0) wsum[tid >> 6] = ss;
  __syncthreads();
  const float total = wsum[0] + wsum[1] + wsum[2] + wsum[3];
  const float r = rsqrtf(total * (1.0f / D_) + 1e-6f);
  const float4* w4 = (const float4*)w;
  us4* o = (us4*)(out + (size_t)s * D_);
  #pragma unroll
  for (int i = 0; i < 4; i++){
    float4 t = v[i], ww = w4[tid + 256*i];
    us4 p;
    p[0] = f2bf(t.x * r * ww.x); p[1] = f2bf(t.y * r * ww.y);
    p[2] = f2bf(t.z * r * ww.z); p[3] = f2bf(t.w * r * ww.w);
    o[tid + 256*i] = p;
  }
}

// ---------------- fp32 -> bf16 cast ----------------
__global__ __launch_bounds__(256) void cast_k(const float* __restrict__ src,
                                              unsigned short* __restrict__ dst, int n4){
  const int i = blockIdx.x * 256 + threadIdx.x;
  if (i >= n4) return;
  float4 t = ((const float4*)src)[i];
  us4 p;
  p[0] = f2bf(t.x); p[1] = f2bf(t.y); p[2] = f2bf(t.z); p[3] = f2bf(t.w);
  ((us4*)dst)[i] = p;
}

// -------- 4-phase register-pipelined bt-GEMM: C[M,N] = A[M,K]*B[N,K]^T --------
// BM=256, BN=NBG*64 (QKV: 192, grid 32x8; WO: 128, grid 32x8); 8 waves (2Mx4N).
// afX/afY A-fragment sets read one phase ahead of their MFMA. bfr loaded
// same-phase in P1/P3 (2*NBG reads, overlapped with the 8 A reads by partial
// lgkm waits the compiler emits).
// CROSS-WAVE SAFETY RULE (round-4 bug): LDS tiles are staged cooperatively, so
// every vmcnt drain sits IMMEDIATELY BEFORE a barrier; every read of staged
// data is AFTER a barrier whose preceding drain covered it (all waves).
//   D1 vmcnt(NBG)@P1:  A(t1) landed  (read P2)        B(t1) in flight
//   D2 vmcnt(4)  @P2:  B(t1) landed  (read P3)        A(t2) in flight
//   D3 vmcnt(NBG)@P3:  A(t2) landed  (read P4 pre)    B(t2) in flight
//   D4 vmcnt(4+NBG)@P4:B(t2) landed  (read P1-next)   A(t3),B(t3) in flight
// Stage-WAR: P2 stages A(t2)->bufA0 (last read P1, lgkm-drained barrier);
// P3 stages B(t2)->bufB0 (last read P1); P4 stages A(t3),B(t3)->buf1 (last
// reads P2/P3). All >=1 barrier after last reader.
#define PH_BAR() do { asm volatile("s_waitcnt lgkmcnt(0)" ::: "memory");     \
                      __builtin_amdgcn_s_barrier();                          \
                      asm volatile("" ::: "memory"); } while(0)

#define VMCNT(n) asm volatile("s_waitcnt vmcnt(" #n ")" ::: "memory")

#define VMCNT_NBG()   do { if constexpr (NBG == 3) { VMCNT(3); }             \
                           else                    { VMCNT(2); } } while(0)
#define VMCNT_4PNBG() do { if constexpr (NBG == 3) { VMCNT(7); }             \
                           else                    { VMCNT(6); } } while(0)

#define STG_A4(db, g, kt)                                                    \
  gl_lds16(gAw + (size_t)((g)*64) * GK + (size_t)(kt)*64,                    \
           sA + (db)*16384 + (g)*4096 + wave*512)

#define STG_B4(db, g, kt)                                                    \
  gl_lds16(gBw + (size_t)((g)*64) * GK + (size_t)(kt)*64,                    \
           sB + (db)*(NBG*4096) + (g)*4096 + wave*512)

#define LOAD_AF(dst, db, mh)                                                 \
  _Pragma("unroll") for (int ks = 0; ks < 2; ++ks)                           \
    _Pragma("unroll") for (int mf = 0; mf < 4; ++mf)                         \
      dst[ks][mf] = *(const short8*)(sA + (db)*16384 + aRowU + ((mh)*4+mf)*1024 + cswzU[ks]);

#define LOAD_BF(db)                                                          \
  _Pragma("unroll") for (int ks = 0; ks < 2; ++ks)                           \
    _Pragma("unroll") for (int nf = 0; nf < NBG; ++nf)                       \
      bfr[ks][nf] = *(const short8*)(sB + (db)*(NBG*4096) + bRowU + nf*1024 + cswzU[ks]);

#define MFMA_S(src, mh) do {                                                 \
  __builtin_amdgcn_s_setprio(1);                                             \
  _Pragma("unroll") for (int mf = 0; mf < 4; ++mf)                           \
    _Pragma("unroll") for (int nf = 0; nf < NBG; ++nf) {                     \
      v4f t = acc[(mh)*4+mf][nf];                                            \
      t = __builtin_amdgcn_mfma_f32_16x16x32_bf16(src[0][mf], bfr[0][nf], t, 0, 0, 0); \
      t = __builtin_amdgcn_mfma_f32_16x16x32_bf16(src[1][mf], bfr[1][nf], t, 0, 0, 0); \
      acc[(mh)*4+mf][nf] = t;                                                \
    }                                                                        \
  __builtin_amdgcn_s_setprio(0);                                             \
} while (0)

template<int NBG>
__global__ __launch_bounds__(512, 2) void gemm4p(const unsigned short* __restrict__ A,
                                                 const unsigned short* __restrict__ B,
                                                 void* __restrict__ Cp,
                                                 int ldc, int f32out){
  constexpr int WN = NBG * 16;                         // per-wave N span
  __shared__ __align__(16) unsigned short sA[2*16384];           // 64 KiB
  __shared__ __align__(16) unsigned short sB[2*NBG*4096];        // 32/48 KiB

  const int tid = threadIdx.x;
  const int wave = tid >> 6, lane = tid & 63;
  const int l15 = lane & 15, quad = lane >> 4;
  const int wm = wave >> 2, wn = wave & 3;

  // XCD swizzle: grid is (32,8) for both GEMMs; 8x4-block chunk per XCD
  const unsigned lin = blockIdx.y * 32u + blockIdx.x;
  const unsigned g = lin & 7u, jj = lin >> 3;          // XCD id, intra-chunk
  const unsigned cx = g & 3u, cy = g >> 2;             // 4x2 chunk grid
  const int m0 = (int)(cy * 4 + (jj >> 3)) * 256;
  const int n0 = (int)(cx * 8 + (jj & 7)) * (NBG * 64);

  // staging: per-lane pre-swizzled global source (LDS dst stays linear)
  const int lrow  = lane >> 3;
  const int lslot = (lane & 7) ^ lrow;
  const size_t laneOff = (size_t)lrow * GK + (size_t)lslot * 8;
  const unsigned short* gAw = A + (size_t)(m0 + wave*8) * GK + laneOff;
  const unsigned short* gBw = B + (size_t)(n0 + wave*8) * GK + laneOff;

  // ds_read addressing (ushort units), swizzle col ^= (l15&7)<<4 bytes
  const int aRowU = (wm*128 + l15) * 64;
  const int bRowU = (wn*WN + l15) * 64;
  int cswzU[2];
  cswzU[0] = (( 0 + quad*16) ^ ((l15 & 7) << 4)) >> 1;
  cswzU[1] = ((64 + quad*16) ^ ((l15 & 7) << 4)) >> 1;

  v4f acc[8][NBG];
  #pragma unroll
  for (int i = 0; i < 8; i++)
    #pragma unroll
    for (int j2 = 0; j2 < NBG; j2++) acc[i][j2] = (v4f){0.f,0.f,0.f,0.f};

  short8 afX[2][4], afY[2][4];   // pipelined A frags: X=mh0, Y=mh1
  short8 bfr[2][NBG];            // B frags of current tile

  // ---- prologue ----
  // tile0 A+B; drain all; pre-read afX; then issue tile1 A+B (steady-state
  // entry condition: outstanding = A(1)x4 + B(1)xNBG).
  STG_A4(0,0,0); STG_A4(0,1,0); STG_A4(0,2,0); STG_A4(0,3,0);
  #pragma unroll
  for (int g2 = 0; g2 < NBG; ++g2) STG_B4(0,g2,0);
  VMCNT(0);
  PH_BAR();
  LOAD_AF(afX, 0, 0);
  STG_A4(1,0,1); STG_A4(1,1,1); STG_A4(1,2,1); STG_A4(1,3,1);
  #pragma unroll
  for (int g2 = 0; g2 < NBG; ++g2) STG_B4(1,g2,1);

  #pragma unroll 1
  for (int i = 0; i < NIT-1; ++i){
    const int t2 = 2*i + 2, t3 = 2*i + 3;
    // P1: bf<-B(buf0); afY<-A(buf0,mh1); MFMA mh0 (held afX); D1
    LOAD_BF(0);
    LOAD_AF(afY, 0, 1);
    MFMA_S(afX, 0);
    VMCNT_NBG();                 // A(t1) landed; B(t1) in flight
    PH_BAR();
    // P2: afX<-A(buf1,mh0); stage A(t2)x4 -> bufA0; MFMA mh1 (held afY+bf); D2
    LOAD_AF(afX, 1, 0);
    STG_A4(0,0,t2); STG_A4(0,1,t2); STG_A4(0,2,t2); STG_A4(0,3,t2);
    MFMA_S(afY, 1);
    VMCNT(4);                    // B(t1) landed; A(t2) in flight
    PH_BAR();
    // P3: bf<-B(buf1); afY<-A(buf1,mh1); stage B(t2)xNBG -> bufB0;
    //     MFMA mh0 (held afX); D3
    LOAD_BF(1);
    LOAD_AF(afY, 1, 1);
    #pragma unroll
    for (int g2 = 0; g2 < NBG; ++g2) STG_B4(0,g2,t2);
    MFMA_S(afX, 0);
    VMCNT_NBG();                 // A(t2) landed; B(t2) in flight
    PH_BAR();
    // P4: pre-read afX<-A(buf0,mh0)=tile t2 (safe: D3 drained in all waves
    //     before P3's barrier); stage A(t3)x4 + B(t3)xNBG -> buf1;
    //     MFMA mh1 (held afY+bf); D4
    LOAD_AF(afX, 0, 0);
    STG_A4(1,0,t3); STG_A4(1,1,t3); STG_A4(1,2,t3); STG_A4(1,3,t3);
    #pragma unroll
    for (int g2 = 0; g2 < NBG; ++g2) STG_B4(1,g2,t3);
    MFMA_S(afY, 1);
    VMCNT_4PNBG();               // B(t2) landed; A(t3),B(t3) in flight
    PH_BAR();
  }

  // ---- peeled final pair (tile 62 in buf0, 63 in buf1; no further stages) ----
  {
    LOAD_BF(0);
    LOAD_AF(afY, 0, 1);
    MFMA_S(afX, 0);
    VMCNT_NBG();                 // A(63) landed
    PH_BAR();
    LOAD_AF(afX, 1, 0);
    MFMA_S(afY, 1);
    VMCNT(0);                    // B(63) landed
    PH_BAR();
    LOAD_BF(1);
    LOAD_AF(afY, 1, 1);
    MFMA_S(afX, 0);
    PH_BAR();
    MFMA_S(afY, 1);
  }

  // ---- epilogue ----
  if (f32out){
    float* Cf = (float*)Cp;
    #pragma unroll
    for (int mf = 0; mf < 8; ++mf)
      #pragma unroll
      for (int r = 0; r < 4; ++r){
        const size_t row = (size_t)(m0 + wm*128 + mf*16 + quad*4 + r);
        float* crow = Cf + row * ldc + n0 + wn*WN + l15;
        #pragma unroll
        for (int nf = 0; nf < NBG; ++nf) crow[nf*16] = acc[mf][nf][r];
      }
  } else {
    unsigned short* Cb = (unsigned short*)Cp;
    #pragma unroll
    for (int mf = 0; mf < 8; ++mf)
      #pragma unroll
      for (int r = 0; r < 4; ++r){
        const size_t row = (size_t)(m0 + wm*128 + mf*16 + quad*4 + r);
        unsigned short* crow = Cb + row * ldc + n0 + wn*WN + l15;
        #pragma unroll
        for (int nf = 0; nf < NBG; ++nf) crow[nf*16] = f2bf(acc[mf][nf][r]);
      }
  }
}

// ---- RoPE on Q (PRE-SCALED by 1/sqrt(HD)*log2e): qkv -> qa[h][s][128] ----
__global__ __launch_bounds__(256) void rope_q_k(const unsigned short* __restrict__ qkv,
                                                unsigned short* __restrict__ qa){
  const int idx = blockIdx.x * 256 + threadIdx.x;
  const int j = idx & 63, h = (idx >> 6) & (H_-1), s = idx >> 11;
  const unsigned pair = *(const unsigned*)(qkv + (size_t)s*NQKV_ + h*HD_ + 2*j);
  const float x0 = bf2f((unsigned short)(pair & 0xffffu));
  const float x1 = bf2f((unsigned short)(pair >> 16));
  const float ang = (float)s * exp2f((float)j * NLOG2T_64);
  const float c = __cosf(ang), sn = __sinf(ang);
  const unsigned o = (unsigned)f2bf((x0*c - x1*sn) * SCALE_L2E)
                   | ((unsigned)f2bf((x0*sn + x1*c) * SCALE_L2E) << 16);
  *(unsigned*)(qa + ((size_t)h*S_ + s)*HD_ + 2*j) = o;
}

// ---------------- RoPE on K: qkv[s][4096+kv*128+..] -> ka[kv][s][128] ------------
__global__ __launch_bounds__(256) void rope_kk(const unsigned short* __restrict__ qkv,
                                               unsigned short* __restrict__ ka){
  const int idx = blockIdx.x * 256 + threadIdx.x;
  const int j = idx & 63, kv = (idx >> 6) & (KV_-1), s = idx >> 9;
  const unsigned pair = *(const unsigned*)(qkv + (size_t)s*NQKV_ + H_*HD_ + kv*HD_ + 2*j);
  const float x0 = bf2f((unsigned short)(pair & 0xffffu));
  const float x1 = bf2f((unsigned short)(pair >> 16));
  const float ang = (float)s * exp2f((float)j * NLOG2T_64);
  const float c = __cosf(ang), sn = __sinf(ang);
  const unsigned o = (unsigned)f2bf(x0*c - x1*sn) | ((unsigned)f2bf(x0*sn + x1*c) << 16);
  *(unsigned*)(ka + ((size_t)kv*S_ + s)*HD_ + 2*j) = o;
}

// ---------------- V transpose: qkv[s][5120+kv*128+d] -> vt[kv][d][s] -------------
__global__ __launch_bounds__(256) void vtrans_k(const unsigned short* __restrict__ qkv,
                                                unsigned short* __restrict__ vt){
  const int idx = blockIdx.x * 256 + threadIdx.x;
  const int s = idx & (S_-1), d = (idx >> 11) & (HD_-1), kv = idx >> 18;
  vt[idx] = qkv[(size_t)s*NQKV_ + (H_+KV_)*HD_ + kv*HD_ + d];
}

// ---------------- flash attention (causal, GQA), paired q-tiles ----------------
__device__ __forceinline__ void stage_kv(const unsigned short* __restrict__ ka,
                                         const unsigned short* __restrict__ vt,
                                         unsigned short* sKbuf, unsigned short* sVbuf,
                                         int hk, int t0, int wave, int lane){
  const int l15 = lane & 15, quad = lane >> 4;
  #pragma unroll
  for (int j = 0; j < 4; j++){
    const int c = wave*4 + j;                 // (kt,kk) = (c>>2, c&3)
    const int kt = c >> 2, kk = c & 3;
    gl_lds16(ka + (size_t)(hk*S_ + t0 + kt*16 + l15)*HD_ + kk*32 + quad*8,
             sKbuf + c*512);
  }
  #pragma unroll
  for (int j = 0; j < 4; j++){
    const int c = wave*4 + j;                 // (nt,kk2) = (c>>1, c&1)
    const int nt = c >> 1, kk2 = c & 1;
    gl_lds16(vt + (size_t)(hk*HD_ + nt*16 + l15)*S_ + t0 + kk2*32 + quad*8,
             sVbuf + c*512);
  }
}

__global__ __launch_bounds__(256, 2) void attn_k(const unsigned short* __restrict__ qa,
                                                 const unsigned short* __restrict__ ka,
                                                 const unsigned short* __restrict__ vt,
                                                 unsigned short* __restrict__ out){
  const int h = blockIdx.x, p = blockIdx.y;
  const int tid = threadIdx.x, wave = tid >> 6, lane = tid & 63;
  const int l15 = lane & 15, quad = lane >> 4;
  const int hk = h >> 2;                      // N_REP = 4
  const int nbB = 32 - p;                     // units for heavy tile (31-p)
  const int total = nbB + p + 1;              // 33 always

  __shared__ __align__(16) unsigned short sK[2][8192];   // 16KB x2
  __shared__ __align__(16) unsigned short sV[2][8192];   // 16KB x2
  __shared__ __align__(16) unsigned short sP[4][1024];   // 2KB per wave
  unsigned short* pl = &sP[wave][0];

  short8 ones;
  #pragma unroll
  for (int i = 0; i < 8; i++) ones[i] = (short)0x3F80;   // bf16 1.0

  int tile = 31 - p;
  short8 qf[4];
  {
    const unsigned short* qb = qa + (size_t)(h*S_ + tile*64 + wave*16 + l15)*HD_ + quad*8;
    #pragma unroll
    for (int kk = 0; kk < 4; kk++) qf[kk] = *(const short8*)(qb + kk*32);
  }

  v4f O[8];
  #pragma unroll
  for (int nt = 0; nt < 8; nt++) O[nt] = (v4f){0.f,0.f,0.f,0.f};
  float mrow[4], lrow[4];
  #pragma unroll
  for (int r = 0; r < 4; r++){ mrow[r] = -1e30f; lrow[r] = 0.f; }

  stage_kv(ka, vt, sK[0], sV[0], hk, 0, wave, lane);
  __syncthreads();

  for (int u = 0; u < total; ++u){
    const int cur = u & 1;
    if (u + 1 < total){
      const int b2 = (u + 1 < nbB) ? u + 1 : u + 1 - nbB;
      stage_kv(ka, vt, sK[cur^1], sV[cur^1], hk, b2*64, wave, lane);
    }

    // ---- QK^T: S[16 q-rows x 64 keys] ----
    const unsigned short* Kb = &sK[cur][0];
    v4f sc[4];
    #pragma unroll
    for (int kt = 0; kt < 4; kt++) sc[kt] = (v4f){0.f,0.f,0.f,0.f};
    #pragma unroll
    for (int kt = 0; kt < 4; kt++)
      #pragma unroll
      for (int kk = 0; kk < 4; kk++){
        const short8 kf = *(const short8*)(Kb + (kt*4 + kk)*512 + lane*8);
        sc[kt] = __builtin_amdgcn_mfma_f32_16x16x32_bf16(qf[kk], kf, sc[kt], 0, 0, 0);
      }

    // ---- online softmax (exp2 domain; Q pre-scaled) ----
    const bool diag = (u == nbB - 1) || (u == total - 1);   // wave-uniform
    float alpha[4];
    #pragma unroll
    for (int r = 0; r < 4; r++){
      float a0 = sc[0][r], a1 = sc[1][r], a2 = sc[2][r], a3 = sc[3][r];
      if (diag){
        const int rloc = wave*16 + quad*4 + r;
        if (     l15 > rloc) a0 = -1e30f;
        if (16 + l15 > rloc) a1 = -1e30f;
        if (32 + l15 > rloc) a2 = -1e30f;
        if (48 + l15 > rloc) a3 = -1e30f;
      }
      float mx = fmaxf(fmaxf(a0, a1), fmaxf(a2, a3));
      #pragma unroll
      for (int off = 1; off < 16; off <<= 1) mx = fmaxf(mx, __shfl_xor(mx, off, 16));
      const float mnew = fmaxf(mrow[r], mx);
      alpha[r] = exp2f(mrow[r] - mnew);
      mrow[r] = mnew;
      const float e0 = exp2f(a0 - mnew);
      const float e1 = exp2f(a1 - mnew);
      const float e2 = exp2f(a2 - mnew);
      const float e3 = exp2f(a3 - mnew);
      const int mr = (quad*4 + r)*8 + (l15 & 7);
      const int hi = (l15 >> 3) * 128;
      pl[      hi       + mr] = f2bf(e0);
      pl[      hi + 256 + mr] = f2bf(e1);
      pl[512 + hi       + mr] = f2bf(e2);
      pl[512 + hi + 256 + mr] = f2bf(e3);
    }
    #pragma unroll
    for (int nt = 0; nt < 8; nt++)
      #pragma unroll
      for (int r = 0; r < 4; r++) O[nt][r] *= alpha[r];

    __builtin_amdgcn_s_waitcnt(0xC07F);       // lgkmcnt(0): per-wave P region ready
    const short8 pf0 = *(const short8*)(pl + lane*8);
    const short8 pf1 = *(const short8*)(pl + 512 + lane*8);

    // ---- row-sum of P via ones-MFMA ----
    v4f rs = (v4f){0.f,0.f,0.f,0.f};
    rs = __builtin_amdgcn_mfma_f32_16x16x32_bf16(pf0, ones, rs, 0, 0, 0);
    rs = __builtin_amdgcn_mfma_f32_16x16x32_bf16(pf1, ones, rs, 0, 0, 0);

    // ---- PV: O[16 q-rows x 128 dims] ----
    const unsigned short* Vb = &sV[cur][0];
    #pragma unroll
    for (int nt = 0; nt < 8; nt++){
      const short8 vf0 = *(const short8*)(Vb + (nt*2    )*512 + lane*8);
      const short8 vf1 = *(const short8*)(Vb + (nt*2 + 1)*512 + lane*8);
      O[nt] = __builtin_amdgcn_mfma_f32_16x16x32_bf16(pf0, vf0, O[nt], 0, 0, 0);
      O[nt] = __builtin_amdgcn_mfma_f32_16x16x32_bf16(pf1, vf1, O[nt], 0, 0, 0);
    }
    #pragma unroll
    for (int r = 0; r < 4; r++) lrow[r] = lrow[r]*alpha[r] + rs[r];

    __syncthreads();   // all waves done with cur before it is overwritten

    if (u == nbB - 1){                        // finalize heavy tile, switch to light
      #pragma unroll
      for (int r = 0; r < 4; r++){
        const float inv = 1.0f / lrow[r];
        const size_t row = (size_t)(tile*64 + wave*16 + quad*4 + r);
        #pragma unroll
        for (int nt = 0; nt < 8; nt++)
          out[row*D_ + h*HD_ + nt*16 + l15] = f2bf(O[nt][r] * inv);
      }
      tile = p;
      const unsigned short* qb = qa + (size_t)(h*S_ + tile*64 + wave*16 + l15)*HD_ + quad*8;
      #pragma unroll
      for (int kk = 0; kk < 4; kk++) qf[kk] = *(const short8*)(qb + kk*32);
      #pragma unroll
      for (int nt = 0; nt < 8; nt++) O[nt] = (v4f){0.f,0.f,0.f,0.f};
      #pragma unroll
      for (int r = 0; r < 4; r++){ mrow[r] = -1e30f; lrow[r] = 0.f; }
    }
  }

  #pragma unroll
  for (int r = 0; r < 4; r++){
    const float inv = 1.0f / lrow[r];
    const size_t row = (size_t)(tile*64 + wave*16 + quad*4 + r);
    #pragma unroll
    for (int nt = 0; nt < 8; nt++)
      out[row*D_ + h*HD_ + nt*16 + l15] = f2bf(O[nt][r] * inv);
  }
}

// ---------------- launch ----------------
// Workspace map (MiB): [0,16) h_bf16 | [16,64) wqkv_bf16 (later: [16,48) wo_bf16,
// [48,64) attn_bf16) | [64,88) qkv_bf16 | [88,104) qa | [104,108) ka | [108,112) vt.
extern "C" void kernel_launch(void* const* d_in, const int* in_sizes, int n_in,
                              void* d_out, int out_size, void* d_ws, size_t ws_size,
                              hipStream_t stream){
  (void)in_sizes; (void)n_in; (void)out_size; (void)ws_size;
  const float* hidden = (const float*)d_in[0];
  const float* norm_w = (const float*)d_in[1];
  const float* wq = (const float*)d_in[2];
  const float* wk = (const float*)d_in[3];
  const float* wv = (const float*)d_in[4];
  const float* wo = (const float*)d_in[5];

  char* ws = (char*)d_ws;
  unsigned short* h_bf  = (unsigned short*)(ws);
  unsigned short* wqkv  = (unsigned short*)(ws + (size_t)(16u) * 1048576u);
  unsigned short* qkv   = (unsigned short*)(ws + (size_t)(64u) * 1048576u);
  unsigned short* qa    = (unsigned short*)(ws + (size_t)(88u) * 1048576u);
  unsigned short* ka    = (unsigned short*)(ws + (size_t)(104u) * 1048576u);
  unsigned short* vt    = (unsigned short*)(ws + (size_t)(108u) * 1048576u);
  unsigned short* wo_bf = (unsigned short*)(ws + (size_t)(16u) * 1048576u);  // reuse
  unsigned short* attnb = (unsigned short*)(ws + (size_t)(48u) * 1048576u);  // reuse

  rmsnorm_k<<<S_, 256, 0, stream>>>(hidden, norm_w, h_bf);

  cast_k<<<(D_*D_/4)/256, 256, 0, stream>>>(wq, wqkv, D_*D_/4);
  cast_k<<<(KV_*HD_*D_/4)/256, 256, 0, stream>>>(wk, wqkv + (size_t)H_*HD_*D_, KV_*HD_*D_/4);
  cast_k<<<(KV_*HD_*D_/4)/256, 256, 0, stream>>>(wv, wqkv + (size_t)(H_+KV_)*HD_*D_, KV_*HD_*D_/4);

  // QKV GEMM: BN=192, grid 32x8 = 256 blocks (perfect fill)
  gemm4p<3><<<dim3(NQKV_/192, S_/256), 512, 0, stream>>>(h_bf, wqkv, qkv, NQKV_, 0);

  rope_q_k<<<(S_*H_*64)/256, 256, 0, stream>>>(qkv, qa);
  rope_kk <<<(S_*KV_*64)/256, 256, 0, stream>>>(qkv, ka);
  vtrans_k<<<(KV_*HD_*S_)/256, 256, 0, stream>>>(qkv, vt);

  cast_k<<<(D_*D_/4)/256, 256, 0, stream>>>(wo, wo_bf, D_*D_/4);

  attn_k<<<dim3(H_, 16), 256, 0, stream>>>(qa, ka, vt, attnb);

  // WO GEMM: BN=128, grid 32x8 = 256 blocks (perfect fill)
  gemm4p<2><<<dim3(D_/128, S_/256), 512, 0, stream>>>(attnb, wo_bf, d_out, D_, 1);
}